// Round 12
// baseline (2495.436 us; speedup 1.0000x reference)
//
#include <hip/hip_runtime.h>
#include <hip/hip_fp16.h>
#include <hip/hip_cooperative_groups.h>

namespace cgrp = cooperative_groups;

#define E_EDGES   400000
#define M_NODES   50000
#define N_INC     800000
#define PER_B     400000
#define VEC_N     800000
#define N4        200000
#define CG_ITERS  11
#define EPSF      1e-12f

// scal (4096 floats): 32 slot-pairs (64 floats) per instance.
//   RHO(t) = scal + 64*t           t=0..12
//   MU(t)  = scal + 1024 + 64*t    t=0..12
//   fin    = scal + 3968 : fin[4t+0/1]=alpha_t(b0/b1), fin[4t+2/3]=rho_t(b0/b1)

__device__ __forceinline__ float waveReduce(float v) {
#pragma unroll
    for (int off = 32; off > 0; off >>= 1)
        v += __shfl_down(v, off, 64);
    return v;
}

__device__ __forceinline__ void blockReduceAdd2(float d0, float d1, float* __restrict__ base) {
    __shared__ float red[8];
    d0 = waveReduce(d0);
    d1 = waveReduce(d1);
    int w = threadIdx.x >> 6, lane = threadIdx.x & 63;
    if (lane == 0) { red[2*w] = d0; red[2*w+1] = d1; }
    __syncthreads();
    if (threadIdx.x == 0) {
        float t0 = red[0] + red[2] + red[4] + red[6];
        float t1 = red[1] + red[3] + red[5] + red[7];
        int s = (blockIdx.x & 31) << 1;
        atomicAdd(&base[s], t0);
        atomicAdd(&base[s + 1], t1);
    }
    __syncthreads();
}

__device__ __forceinline__ float2 sumSlots(const float* __restrict__ base) {
    float a = 0.0f, b = 0.0f;
#pragma unroll
    for (int k = 0; k < 32; ++k) { a += base[2*k]; b += base[2*k+1]; }
    return make_float2(a, b);
}

__device__ __forceinline__ void writeHalf4(__half* __restrict__ rh, int i4, float4 v) {
    union { float2 f2; __half2 h[2]; } u;
    u.h[0] = __floats2half2_rn(v.x, v.y);
    u.h[1] = __floats2half2_rn(v.z, v.w);
    *(float2*)(rh + (i4 << 2)) = u.f2;
}

// ---------------- precompute kernels ----------------

__global__ void k_zero(float* __restrict__ s, int* __restrict__ cnt) {
    int i = blockIdx.x * blockDim.x + threadIdx.x;
    if (i < 4096) s[i] = 0.0f;
    if (i < M_NODES) cnt[i] = 0;
}

__global__ void k_hist(const int* __restrict__ src, const int* __restrict__ dst,
                       int* __restrict__ cnt) {
    int e = blockIdx.x * blockDim.x + threadIdx.x;
    if (e < E_EDGES) {
        atomicAdd(&cnt[src[e]], 1);
        atomicAdd(&cnt[dst[e]], 1);
    }
}

#define SCAN_T 1024
__global__ void k_scan(const int* __restrict__ cnt, int* __restrict__ off,
                       int* __restrict__ cursor) {
    __shared__ int part[SCAN_T];
    int t = threadIdx.x;
    const int chunk = (M_NODES + SCAN_T - 1) / SCAN_T;
    int beg = t * chunk;
    int end = beg + chunk; if (end > M_NODES) end = M_NODES;
    if (beg > M_NODES) beg = M_NODES;
    int s = 0;
    for (int i = beg; i < end; ++i) s += cnt[i];
    part[t] = s;
    __syncthreads();
    for (int st = 1; st < SCAN_T; st <<= 1) {
        int v = (t >= st) ? part[t - st] : 0;
        __syncthreads();
        part[t] += v;
        __syncthreads();
    }
    int run = (t == 0) ? 0 : part[t - 1];
    for (int i = beg; i < end; ++i) {
        off[i] = run; cursor[i] = run;
        run += cnt[i];
    }
    if (t == SCAN_T - 1) off[M_NODES] = run;
}

__global__ void k_scatter(const int* __restrict__ src, const int* __restrict__ dst,
                          int* __restrict__ cursor, int* __restrict__ pos0,
                          int* __restrict__ pos1, int* __restrict__ nb,
                          int* __restrict__ wk) {
    int e = blockIdx.x * blockDim.x + threadIdx.x;
    if (e < E_EDGES) {
        int s = src[e], t = dst[e];
        int p0 = atomicAdd(&cursor[s], 1);
        pos0[e] = p0; nb[p0] = t; wk[p0] = e;
        int p1 = atomicAdd(&cursor[t], 1);
        pos1[e] = p1; nb[p1] = s; wk[p1] = e + E_EDGES;
    }
}

__global__ __launch_bounds__(256) void k_buildC(const float* __restrict__ Rs,
                                                const float* __restrict__ Rd,
                                                const int* __restrict__ pos0,
                                                const int* __restrict__ pos1,
                                                __half* __restrict__ Wc,
                                                __half* __restrict__ GHc, int haveGH) {
    int gt = blockIdx.x * blockDim.x + threadIdx.x;
    int e = gt >> 3, a = gt & 7;
    if (e >= E_EDGES) return;
    const float* rs = Rs + ((size_t)e << 6);
    const float* rd = Rd + ((size_t)e << 6);
    float C[8], Ct[8], G[8], H[8];
#pragma unroll
    for (int j = 0; j < 8; ++j) { C[j] = 0; Ct[j] = 0; G[j] = 0; H[j] = 0; }
#pragma unroll
    for (int c = 0; c < 8; ++c) {
        float xs = rs[c * 8 + a];
        float xd = rd[c * 8 + a];
        float4 s0 = *(const float4*)(rs + c * 8);
        float4 s1 = *(const float4*)(rs + c * 8 + 4);
        float4 d0 = *(const float4*)(rd + c * 8);
        float4 d1 = *(const float4*)(rd + c * 8 + 4);
        C[0] += xs * d0.x; C[1] += xs * d0.y; C[2] += xs * d0.z; C[3] += xs * d0.w;
        C[4] += xs * d1.x; C[5] += xs * d1.y; C[6] += xs * d1.z; C[7] += xs * d1.w;
        Ct[0] += xd * s0.x; Ct[1] += xd * s0.y; Ct[2] += xd * s0.z; Ct[3] += xd * s0.w;
        Ct[4] += xd * s1.x; Ct[5] += xd * s1.y; Ct[6] += xd * s1.z; Ct[7] += xd * s1.w;
        G[0] += xs * s0.x; G[1] += xs * s0.y; G[2] += xs * s0.z; G[3] += xs * s0.w;
        G[4] += xs * s1.x; G[5] += xs * s1.y; G[6] += xs * s1.z; G[7] += xs * s1.w;
        H[0] += xd * d0.x; H[1] += xd * d0.y; H[2] += xd * d0.z; H[3] += xd * d0.w;
        H[4] += xd * d1.x; H[5] += xd * d1.y; H[6] += xd * d1.z; H[7] += xd * d1.w;
    }
    size_t s0o = (size_t)pos0[e] << 6;
    size_t s1o = (size_t)pos1[e] << 6;
    union { float4 f; __half2 h[4]; } u;
#pragma unroll
    for (int k = 0; k < 4; ++k) u.h[k] = __floats2half2_rn(C[2*k], C[2*k+1]);
    *(float4*)(Wc + s0o + (a << 3)) = u.f;
#pragma unroll
    for (int k = 0; k < 4; ++k) u.h[k] = __floats2half2_rn(Ct[2*k], Ct[2*k+1]);
    *(float4*)(Wc + s1o + (a << 3)) = u.f;
    if (haveGH) {
#pragma unroll
        for (int k = 0; k < 4; ++k) u.h[k] = __floats2half2_rn(G[2*k], G[2*k+1]);
        *(float4*)(GHc + s0o + (a << 3)) = u.f;
#pragma unroll
        for (int k = 0; k < 4; ++k) u.h[k] = __floats2half2_rn(H[2*k], H[2*k+1]);
        *(float4*)(GHc + s1o + (a << 3)) = u.f;
    }
}

__global__ __launch_bounds__(256) void k_diagS(const int* __restrict__ off,
                                               const __half* __restrict__ GHc,
                                               __half* __restrict__ diag) {
    int wave = (blockIdx.x * blockDim.x + threadIdx.x) >> 6;
    int lane = threadIdx.x & 63;
    int g = lane >> 3, a = lane & 7;
    int m = wave;
    if (m >= M_NODES) return;
    float D[8];
#pragma unroll
    for (int j = 0; j < 8; ++j) D[j] = 0.0f;
    int beg = off[m], end = off[m + 1];
    for (int i = beg + g; i < end; i += 8) {
        union { float4 f; __half2 h[4]; } u;
        u.f = *(const float4*)(GHc + ((size_t)i << 6) + (a << 3));
        float2 w0 = __half22float2(u.h[0]);
        float2 w1 = __half22float2(u.h[1]);
        float2 w2 = __half22float2(u.h[2]);
        float2 w3 = __half22float2(u.h[3]);
        D[0] += w0.x; D[1] += w0.y; D[2] += w1.x; D[3] += w1.y;
        D[4] += w2.x; D[5] += w2.y; D[6] += w3.x; D[7] += w3.y;
    }
#pragma unroll
    for (int j = 0; j < 8; ++j) {
        D[j] += __shfl_xor(D[j], 8, 64);
        D[j] += __shfl_xor(D[j], 16, 64);
        D[j] += __shfl_xor(D[j], 32, 64);
    }
    if (g == 0) {
        D[a] += 1.0f;
        union { float4 f; __half2 h[4]; } u;
#pragma unroll
        for (int k = 0; k < 4; ++k) u.h[k] = __floats2half2_rn(D[2*k], D[2*k+1]);
        *(float4*)(diag + ((size_t)m << 6) + (a << 3)) = u.f;
    }
}

__global__ void k_diagR(const int* __restrict__ off, const int* __restrict__ wk,
                        const float* __restrict__ Rs, const float* __restrict__ Rd,
                        __half* __restrict__ diag) {
    int gt = blockIdx.x * blockDim.x + threadIdx.x;
    int m = gt >> 3, a = gt & 7;
    if (m >= M_NODES) return;
    float D[8];
#pragma unroll
    for (int j = 0; j < 8; ++j) D[j] = 0.0f;
    int beg = off[m], end = off[m + 1];
    for (int i = beg; i < end; ++i) {
        int k = wk[i];
        int side = (k >= E_EDGES);
        int e = k - (side ? E_EDGES : 0);
        const float* R = (side ? Rd : Rs) + ((size_t)e << 6);
#pragma unroll
        for (int c = 0; c < 8; ++c) {
            float xa = R[c * 8 + a];
            float4 y0 = *(const float4*)(R + c * 8);
            float4 y1 = *(const float4*)(R + c * 8 + 4);
            D[0] += xa * y0.x; D[1] += xa * y0.y; D[2] += xa * y0.z; D[3] += xa * y0.w;
            D[4] += xa * y1.x; D[5] += xa * y1.y; D[6] += xa * y1.z; D[7] += xa * y1.w;
        }
    }
    D[a] += 1.0f;
    union { float4 f; __half2 h[4]; } u;
#pragma unroll
    for (int k = 0; k < 4; ++k) u.h[k] = __floats2half2_rn(D[2*k], D[2*k+1]);
    *(float4*)(diag + ((size_t)m << 6) + (a << 3)) = u.f;
}

// ---------------- fused cooperative CG ----------------

// w = A r via fp16 mirror rh; optional fused dot mu = w.r
__device__ __forceinline__ void mv_phase(const __half* __restrict__ rh,
                                         float* __restrict__ wv,
                                         const int* __restrict__ off,
                                         const int* __restrict__ nbA,
                                         const __half* __restrict__ Wc,
                                         const __half* __restrict__ diag,
                                         float* __restrict__ mu, int doMu) {
    int lane = threadIdx.x & 63;
    int g = lane >> 3, a = lane & 7;
    int waveId = (blockIdx.x * blockDim.x + threadIdx.x) >> 6;
    int nWaves = (gridDim.x * blockDim.x) >> 6;
    float mu0 = 0.f, mu1 = 0.f;
    for (int m = waveId; m < M_NODES; m += nWaves) {
        int beg = off[m], end = off[m + 1];
        float acc0 = 0.f, acc1 = 0.f;
        int i = beg + g;
        for (; i + 8 < end; i += 16) {
            int nA = nbA[i];
            int nB = nbA[i + 8];
            union { float4 f; __half2 h[4]; } uA, uB, rA0, rA1, rB0, rB1;
            uA.f = *(const float4*)(Wc + ((size_t)i << 6) + (a << 3));
            uB.f = *(const float4*)(Wc + ((size_t)(i + 8) << 6) + (a << 3));
            rA0.f = *(const float4*)(rh + (nA << 4));
            rA1.f = *(const float4*)(rh + (nA << 4) + 8);
            rB0.f = *(const float4*)(rh + (nB << 4));
            rB1.f = *(const float4*)(rh + (nB << 4) + 8);
            float2 wA0 = __half22float2(uA.h[0]);
            float2 wA1 = __half22float2(uA.h[1]);
            float2 wA2 = __half22float2(uA.h[2]);
            float2 wA3 = __half22float2(uA.h[3]);
            float2 a00 = __half22float2(rA0.h[0]);
            float2 a01 = __half22float2(rA0.h[1]);
            float2 a02 = __half22float2(rA0.h[2]);
            float2 a03 = __half22float2(rA0.h[3]);
            float2 a10 = __half22float2(rA1.h[0]);
            float2 a11 = __half22float2(rA1.h[1]);
            float2 a12 = __half22float2(rA1.h[2]);
            float2 a13 = __half22float2(rA1.h[3]);
            acc0 += wA0.x*a00.x + wA0.y*a00.y + wA1.x*a01.x + wA1.y*a01.y
                  + wA2.x*a02.x + wA2.y*a02.y + wA3.x*a03.x + wA3.y*a03.y;
            acc1 += wA0.x*a10.x + wA0.y*a10.y + wA1.x*a11.x + wA1.y*a11.y
                  + wA2.x*a12.x + wA2.y*a12.y + wA3.x*a13.x + wA3.y*a13.y;
            float2 wB0 = __half22float2(uB.h[0]);
            float2 wB1 = __half22float2(uB.h[1]);
            float2 wB2 = __half22float2(uB.h[2]);
            float2 wB3 = __half22float2(uB.h[3]);
            float2 b00 = __half22float2(rB0.h[0]);
            float2 b01 = __half22float2(rB0.h[1]);
            float2 b02 = __half22float2(rB0.h[2]);
            float2 b03 = __half22float2(rB0.h[3]);
            float2 b10 = __half22float2(rB1.h[0]);
            float2 b11 = __half22float2(rB1.h[1]);
            float2 b12 = __half22float2(rB1.h[2]);
            float2 b13 = __half22float2(rB1.h[3]);
            acc0 += wB0.x*b00.x + wB0.y*b00.y + wB1.x*b01.x + wB1.y*b01.y
                  + wB2.x*b02.x + wB2.y*b02.y + wB3.x*b03.x + wB3.y*b03.y;
            acc1 += wB0.x*b10.x + wB0.y*b10.y + wB1.x*b11.x + wB1.y*b11.y
                  + wB2.x*b12.x + wB2.y*b12.y + wB3.x*b13.x + wB3.y*b13.y;
        }
        if (i < end) {
            int n = nbA[i];
            union { float4 f; __half2 h[4]; } u, r0, r1;
            u.f = *(const float4*)(Wc + ((size_t)i << 6) + (a << 3));
            r0.f = *(const float4*)(rh + (n << 4));
            r1.f = *(const float4*)(rh + (n << 4) + 8);
            float2 w0 = __half22float2(u.h[0]);
            float2 w1 = __half22float2(u.h[1]);
            float2 w2 = __half22float2(u.h[2]);
            float2 w3 = __half22float2(u.h[3]);
            float2 c00 = __half22float2(r0.h[0]);
            float2 c01 = __half22float2(r0.h[1]);
            float2 c02 = __half22float2(r0.h[2]);
            float2 c03 = __half22float2(r0.h[3]);
            float2 c10 = __half22float2(r1.h[0]);
            float2 c11 = __half22float2(r1.h[1]);
            float2 c12 = __half22float2(r1.h[2]);
            float2 c13 = __half22float2(r1.h[3]);
            acc0 += w0.x*c00.x + w0.y*c00.y + w1.x*c01.x + w1.y*c01.y
                  + w2.x*c02.x + w2.y*c02.y + w3.x*c03.x + w3.y*c03.y;
            acc1 += w0.x*c10.x + w0.y*c10.y + w1.x*c11.x + w1.y*c11.y
                  + w2.x*c12.x + w2.y*c12.y + w3.x*c13.x + w3.y*c13.y;
        }
        acc0 += __shfl_xor(acc0, 8, 64);  acc1 += __shfl_xor(acc1, 8, 64);
        acc0 += __shfl_xor(acc0, 16, 64); acc1 += __shfl_xor(acc1, 16, 64);
        acc0 += __shfl_xor(acc0, 32, 64); acc1 += __shfl_xor(acc1, 32, 64);
        if (g < 2) {
            union { float4 f; __half2 h[4]; } ur, ud;
            ur.f = *(const float4*)(rh + (m << 4) + (g << 3));
            ud.f = *(const float4*)(diag + ((size_t)m << 6) + (a << 3));
            float rm[8];
            float2 t;
            t = __half22float2(ur.h[0]); rm[0] = t.x; rm[1] = t.y;
            t = __half22float2(ur.h[1]); rm[2] = t.x; rm[3] = t.y;
            t = __half22float2(ur.h[2]); rm[4] = t.x; rm[5] = t.y;
            t = __half22float2(ur.h[3]); rm[6] = t.x; rm[7] = t.y;
            float2 g0 = __half22float2(ud.h[0]);
            float2 g1 = __half22float2(ud.h[1]);
            float2 g2 = __half22float2(ud.h[2]);
            float2 g3 = __half22float2(ud.h[3]);
            float acc = g ? acc1 : acc0;
            float w = g0.x*rm[0] + g0.y*rm[1] + g1.x*rm[2] + g1.y*rm[3]
                    + g2.x*rm[4] + g2.y*rm[5] + g3.x*rm[6] + g3.y*rm[7] - acc;
            wv[(m << 4) + (g << 3) + a] = w;
            float ra = rm[a];
            if (g == 0) mu0 += ra * w; else mu1 += ra * w;
        }
    }
    if (doMu) blockReduceAdd2(mu0, mu1, mu);
}

// C-G update phase (grid-stride). On last iter writes de-interleaved x to out.
__device__ __forceinline__ void axpy_phase(float4* __restrict__ x,
                                           float4* __restrict__ r,
                                           __half* __restrict__ rh,
                                           float4* __restrict__ p,
                                           float4* __restrict__ q,
                                           const float4* __restrict__ w,
                                           const float* __restrict__ rho_s,
                                           const float* __restrict__ mu_s,
                                           float* __restrict__ fin,
                                           float* __restrict__ rho_next,
                                           int j, int last,
                                           float4* __restrict__ out,
                                           int tid, int nthr) {
    __shared__ float sc[4];
    if (threadIdx.x == 0) {
        float2 rho = sumSlots(rho_s);
        float2 mu  = sumSlots(mu_s);
        float b0, b1, al0, al1;
        if (j == 0) {
            b0 = b1 = 0.0f;
            al0 = rho.x / (mu.x + EPSF);
            al1 = rho.y / (mu.y + EPSF);
        } else {
            float ap0 = fin[4*(j-1)+0], ap1 = fin[4*(j-1)+1];
            float rp0 = fin[4*(j-1)+2], rp1 = fin[4*(j-1)+3];
            b0 = rho.x / (rp0 + EPSF);
            b1 = rho.y / (rp1 + EPSF);
            al0 = rho.x / (mu.x - b0 * rho.x / (ap0 + EPSF) + EPSF);
            al1 = rho.y / (mu.y - b1 * rho.y / (ap1 + EPSF) + EPSF);
        }
        if (!last && blockIdx.x == 0) {
            fin[4*j] = al0; fin[4*j+1] = al1; fin[4*j+2] = rho.x; fin[4*j+3] = rho.y;
        }
        sc[0] = al0; sc[1] = al1; sc[2] = b0; sc[3] = b1;
    }
    __syncthreads();
    float al0 = sc[0], al1 = sc[1], b0 = sc[2], b1 = sc[3];
    float s0 = 0.f, s1 = 0.f;
    for (int i = tid; i < N4; i += nthr) {
        int batch = (i >> 1) & 1;
        float be = batch ? b1 : b0;
        float al = batch ? al1 : al0;
        float4 rv = r[i], wv = w[i], xv = x[i];
        float4 pn, qn;
        if (j == 0) { pn = rv; qn = wv; }
        else {
            float4 pv = p[i], qv = q[i];
            pn = make_float4(rv.x + be*pv.x, rv.y + be*pv.y, rv.z + be*pv.z, rv.w + be*pv.w);
            qn = make_float4(wv.x + be*qv.x, wv.y + be*qv.y, wv.z + be*qv.z, wv.w + be*qv.w);
        }
        float4 xn = make_float4(xv.x + al*pn.x, xv.y + al*pn.y, xv.z + al*pn.z, xv.w + al*pn.w);
        if (last) {
            int m = i >> 2, slot = i & 3;
            int b = slot >> 1, h = slot & 1;
            out[b * (PER_B / 4) + (m << 1) + h] = xn;
        } else {
            float4 rn = make_float4(rv.x - al*qn.x, rv.y - al*qn.y,
                                    rv.z - al*qn.z, rv.w - al*qn.w);
            x[i] = xn; r[i] = rn; p[i] = pn; q[i] = qn;
            writeHalf4(rh, i, rn);
            float d = rn.x*rn.x + rn.y*rn.y + rn.z*rn.z + rn.w*rn.w;
            if (batch == 0) s0 += d; else s1 += d;
        }
    }
    if (!last) blockReduceAdd2(s0, s1, rho_next);
}

__global__ __launch_bounds__(256, 3) void k_cg(const float4* __restrict__ c0,
                                               __half* __restrict__ bh,
                                               float4* __restrict__ r,
                                               __half* __restrict__ rh,
                                               float4* __restrict__ x,
                                               float4* __restrict__ p,
                                               float4* __restrict__ q,
                                               float* __restrict__ wv,
                                               const int* __restrict__ off,
                                               const int* __restrict__ nbA,
                                               const __half* __restrict__ Wc,
                                               const __half* __restrict__ diag,
                                               float* __restrict__ scal,
                                               float4* __restrict__ out) {
    cgrp::grid_group grid = cgrp::this_grid();
    const int tid = blockIdx.x * blockDim.x + threadIdx.x;
    const int nthr = gridDim.x * blockDim.x;
    float* RHO = scal;
    float* MU  = scal + 1024;
    float* FIN = scal + 3968;

    // phase 0: bh = fp16(interleave(c0))
    for (int d = tid; d < N4; d += nthr) {
        int m = d >> 2, slot = d & 3, b = slot >> 1, h = slot & 1;
        float4 v = c0[b * (PER_B / 4) + (m << 1) + h];
        writeHalf4(bh, d, v);
    }
    grid.sync();

    // phase 1: w = A b (no dot)
    mv_phase(bh, wv, off, nbA, Wc, diag, MU + 64 * 12, 0);
    grid.sync();

    // phase 2: r = b - w ; x = b ; rh ; rho0
    {
        float s0 = 0.f, s1 = 0.f;
        const float4* w4 = (const float4*)wv;
        for (int d = tid; d < N4; d += nthr) {
            int m = d >> 2, slot = d & 3, b = slot >> 1, h = slot & 1;
            float4 bv = c0[b * (PER_B / 4) + (m << 1) + h];
            float4 a = w4[d];
            float4 rv = make_float4(bv.x - a.x, bv.y - a.y, bv.z - a.z, bv.w - a.w);
            r[d] = rv; x[d] = bv;
            writeHalf4(rh, d, rv);
            float dd = rv.x*rv.x + rv.y*rv.y + rv.z*rv.z + rv.w*rv.w;
            if (((d >> 1) & 1) == 0) s0 += dd; else s1 += dd;
        }
        blockReduceAdd2(s0, s1, RHO);
    }
    grid.sync();

    // C-G CG loop
    for (int t = 0; t < CG_ITERS; ++t) {
        mv_phase(rh, wv, off, nbA, Wc, diag, MU + 64 * t, 1);
        grid.sync();
        axpy_phase(x, r, rh, p, q, (const float4*)wv,
                   RHO + 64 * t, MU + 64 * t, FIN, RHO + 64 * (t + 1),
                   t, (t == CG_ITERS - 1) ? 1 : 0, out, tid, nthr);
        grid.sync();
    }
}

extern "C" void kernel_launch(void* const* d_in, const int* in_sizes, int n_in,
                              void* d_out, int out_size, void* d_ws, size_t ws_size,
                              hipStream_t stream) {
    const float* c0 = (const float*)d_in[0];
    const int* src  = (const int*)d_in[1];
    const int* dst  = (const int*)d_in[2];
    const float* Rs = (const float*)d_in[3];
    const float* Rd = (const float*)d_in[4];

    char* wsp = (char*)d_ws;
    size_t o = 0;
    auto alloc = [&](size_t bytes) { char* c = wsp + o; o = (o + bytes + 255) & ~(size_t)255; return c; };
    float* r      = (float*)alloc(VEC_N * 4);
    float* wv     = (float*)alloc(VEC_N * 4);
    float* p      = (float*)alloc(VEC_N * 4);
    float* q      = (float*)alloc(VEC_N * 4);
    float* x      = (float*)alloc(VEC_N * 4);
    __half* rh    = (__half*)alloc(VEC_N * 2);
    __half* bh    = (__half*)alloc(VEC_N * 2);
    float* scal   = (float*)alloc(4096 * 4);
    int*   cnt    = (int*)alloc(M_NODES * 4);
    int*   offa   = (int*)alloc((M_NODES + 1) * 4);
    int*   cursor = (int*)alloc(M_NODES * 4);
    int*   pos0   = (int*)alloc(E_EDGES * 4);
    int*   pos1   = (int*)alloc(E_EDGES * 4);
    int*   wk     = (int*)alloc(N_INC * 4);
    int*   nb     = (int*)alloc(N_INC * 4);
    __half* diag  = (__half*)alloc((size_t)M_NODES * 64 * 2);
    __half* Wc    = (__half*)alloc((size_t)N_INC * 64 * 2);
    size_t ghBytes = (size_t)N_INC * 64 * 2;
    int haveGH = (o + ghBytes) <= ws_size;
    __half* GHc = haveGH ? (__half*)alloc(ghBytes) : (__half*)Wc;

    const int BLK = 256;
    const int grid_e  = (E_EDGES + BLK - 1) / BLK;
    const int grid_m  = (M_NODES + BLK - 1) / BLK;
    const int grid_e8 = (E_EDGES * 8 + BLK - 1) / BLK;
    const int grid_m8 = (M_NODES * 8 + BLK - 1) / BLK;
    const int grid_mw = (M_NODES * 64 + BLK - 1) / BLK;

    // ---- precompute (rebuilt every call) ----
    k_zero<<<grid_m, BLK, 0, stream>>>(scal, cnt);
    k_hist<<<grid_e, BLK, 0, stream>>>(src, dst, cnt);
    k_scan<<<1, SCAN_T, 0, stream>>>(cnt, offa, cursor);
    k_scatter<<<grid_e, BLK, 0, stream>>>(src, dst, cursor, pos0, pos1, nb, wk);
    k_buildC<<<grid_e8, BLK, 0, stream>>>(Rs, Rd, pos0, pos1, Wc, GHc, haveGH);
    if (haveGH)
        k_diagS<<<grid_mw, BLK, 0, stream>>>(offa, GHc, diag);
    else
        k_diagR<<<grid_m8, BLK, 0, stream>>>(offa, wk, Rs, Rd, diag);

    // ---- fused cooperative CG ----
    int occ = 0;
    (void)hipOccupancyMaxActiveBlocksPerMultiprocessor(&occ, k_cg, 256, 0);
    if (occ < 1) occ = 1;
    int nCU = 0;
    if (hipDeviceGetAttribute(&nCU, hipDeviceAttributeMultiprocessorCount, 0) != hipSuccess || nCU <= 0)
        nCU = 256;
    int blocks = occ * nCU;
    if (blocks > 768) blocks = 768;

    const float4* c0_4 = (const float4*)c0;
    float4* r4 = (float4*)r;
    float4* x4 = (float4*)x;
    float4* p4 = (float4*)p;
    float4* q4 = (float4*)q;
    float4* out4 = (float4*)d_out;
    void* args[] = { (void*)&c0_4, (void*)&bh, (void*)&r4, (void*)&rh, (void*)&x4,
                     (void*)&p4, (void*)&q4, (void*)&wv, (void*)&offa, (void*)&nb,
                     (void*)&Wc, (void*)&diag, (void*)&scal, (void*)&out4 };
    hipLaunchCooperativeKernel((void*)k_cg, dim3(blocks), dim3(BLK), args, 0, stream);
}

// Round 13
// 1060.161 us; speedup vs baseline: 2.3538x; 2.3538x over previous
//
#include <hip/hip_runtime.h>
#include <hip/hip_fp16.h>

#define E_EDGES   400000
#define M_NODES   50000
#define N_INC     800000
#define PER_B     400000
#define VEC_N     800000
#define N4        200000
#define CG_ITERS  11
#define EPSF      1e-12f

// scal (4096 floats): 32 slot-pairs (64 floats) per instance.
//   RHO(t) = scal + 64*t           t=0..12
//   MU(t)  = scal + 1024 + 64*t    t=0..12  (t=12 = init-mv scratch)
//   fin    = scal + 3968 : fin[4t+0/1]=alpha_t(b0/b1), fin[4t+2/3]=rho_t(b0/b1)

__device__ __forceinline__ float waveReduce(float v) {
#pragma unroll
    for (int off = 32; off > 0; off >>= 1)
        v += __shfl_down(v, off, 64);
    return v;
}

__device__ __forceinline__ void blockReduceAdd2(float d0, float d1, float* __restrict__ base) {
    __shared__ float red[8];
    d0 = waveReduce(d0);
    d1 = waveReduce(d1);
    int w = threadIdx.x >> 6, lane = threadIdx.x & 63;
    if (lane == 0) { red[2*w] = d0; red[2*w+1] = d1; }
    __syncthreads();
    if (threadIdx.x == 0) {
        float t0 = red[0] + red[2] + red[4] + red[6];
        float t1 = red[1] + red[3] + red[5] + red[7];
        int s = (blockIdx.x & 31) << 1;
        atomicAdd(&base[s], t0);
        atomicAdd(&base[s + 1], t1);
    }
}

__device__ __forceinline__ float2 sumSlots(const float* __restrict__ base) {
    float a = 0.0f, b = 0.0f;
#pragma unroll
    for (int k = 0; k < 32; ++k) { a += base[2*k]; b += base[2*k+1]; }
    return make_float2(a, b);
}

__device__ __forceinline__ void writeHalf4(__half* __restrict__ rh, int i4, float4 v) {
    union { float2 f2; __half2 h[2]; } u;
    u.h[0] = __floats2half2_rn(v.x, v.y);
    u.h[1] = __floats2half2_rn(v.z, v.w);
    *(float2*)(rh + (i4 << 2)) = u.f2;
}

// zero scal (4096 floats) + cnt (M_NODES ints) in one launch
__global__ void k_zero(float* __restrict__ s, int* __restrict__ cnt) {
    int i = blockIdx.x * blockDim.x + threadIdx.x;
    if (i < 4096) s[i] = 0.0f;
    if (i < M_NODES) cnt[i] = 0;
}

__global__ void k_hist(const int* __restrict__ src, const int* __restrict__ dst,
                       int* __restrict__ cnt) {
    int e = blockIdx.x * blockDim.x + threadIdx.x;
    if (e < E_EDGES) {
        atomicAdd(&cnt[src[e]], 1);
        atomicAdd(&cnt[dst[e]], 1);
    }
}

#define SCAN_T 1024
__global__ void k_scan(const int* __restrict__ cnt, int* __restrict__ off,
                       int* __restrict__ cursor) {
    __shared__ int part[SCAN_T];
    int t = threadIdx.x;
    const int chunk = (M_NODES + SCAN_T - 1) / SCAN_T;
    int beg = t * chunk;
    int end = beg + chunk; if (end > M_NODES) end = M_NODES;
    if (beg > M_NODES) beg = M_NODES;
    int s = 0;
    for (int i = beg; i < end; ++i) s += cnt[i];
    part[t] = s;
    __syncthreads();
    for (int st = 1; st < SCAN_T; st <<= 1) {
        int v = (t >= st) ? part[t - st] : 0;
        __syncthreads();
        part[t] += v;
        __syncthreads();
    }
    int run = (t == 0) ? 0 : part[t - 1];
    for (int i = beg; i < end; ++i) {
        off[i] = run; cursor[i] = run;
        run += cnt[i];
    }
    if (t == SCAN_T - 1) off[M_NODES] = run;
}

__global__ void k_scatter(const int* __restrict__ src, const int* __restrict__ dst,
                          int* __restrict__ cursor, int* __restrict__ pos0,
                          int* __restrict__ pos1, int* __restrict__ nb,
                          int* __restrict__ wk) {
    int e = blockIdx.x * blockDim.x + threadIdx.x;
    if (e < E_EDGES) {
        int s = src[e], t = dst[e];
        int p0 = atomicAdd(&cursor[s], 1);
        pos0[e] = p0; nb[p0] = t; wk[p0] = e;
        int p1 = atomicAdd(&cursor[t], 1);
        pos1[e] = p1; nb[p1] = s; wk[p1] = e + E_EDGES;
    }
}

// 8 lanes/edge, coalesced sequential R reads; scatter-write 128B blocks to CSR slots.
__global__ __launch_bounds__(256) void k_buildC(const float* __restrict__ Rs,
                                                const float* __restrict__ Rd,
                                                const int* __restrict__ pos0,
                                                const int* __restrict__ pos1,
                                                __half* __restrict__ Wc,
                                                __half* __restrict__ GHc, int haveGH) {
    int gt = blockIdx.x * blockDim.x + threadIdx.x;
    int e = gt >> 3, a = gt & 7;
    if (e >= E_EDGES) return;
    const float* rs = Rs + ((size_t)e << 6);
    const float* rd = Rd + ((size_t)e << 6);
    float C[8], Ct[8], G[8], H[8];
#pragma unroll
    for (int j = 0; j < 8; ++j) { C[j] = 0; Ct[j] = 0; G[j] = 0; H[j] = 0; }
#pragma unroll
    for (int c = 0; c < 8; ++c) {
        float xs = rs[c * 8 + a];
        float xd = rd[c * 8 + a];
        float4 s0 = *(const float4*)(rs + c * 8);
        float4 s1 = *(const float4*)(rs + c * 8 + 4);
        float4 d0 = *(const float4*)(rd + c * 8);
        float4 d1 = *(const float4*)(rd + c * 8 + 4);
        C[0] += xs * d0.x; C[1] += xs * d0.y; C[2] += xs * d0.z; C[3] += xs * d0.w;
        C[4] += xs * d1.x; C[5] += xs * d1.y; C[6] += xs * d1.z; C[7] += xs * d1.w;
        Ct[0] += xd * s0.x; Ct[1] += xd * s0.y; Ct[2] += xd * s0.z; Ct[3] += xd * s0.w;
        Ct[4] += xd * s1.x; Ct[5] += xd * s1.y; Ct[6] += xd * s1.z; Ct[7] += xd * s1.w;
        G[0] += xs * s0.x; G[1] += xs * s0.y; G[2] += xs * s0.z; G[3] += xs * s0.w;
        G[4] += xs * s1.x; G[5] += xs * s1.y; G[6] += xs * s1.z; G[7] += xs * s1.w;
        H[0] += xd * d0.x; H[1] += xd * d0.y; H[2] += xd * d0.z; H[3] += xd * d0.w;
        H[4] += xd * d1.x; H[5] += xd * d1.y; H[6] += xd * d1.z; H[7] += xd * d1.w;
    }
    size_t s0o = (size_t)pos0[e] << 6;
    size_t s1o = (size_t)pos1[e] << 6;
    union { float4 f; __half2 h[4]; } u;
#pragma unroll
    for (int k = 0; k < 4; ++k) u.h[k] = __floats2half2_rn(C[2*k], C[2*k+1]);
    *(float4*)(Wc + s0o + (a << 3)) = u.f;
#pragma unroll
    for (int k = 0; k < 4; ++k) u.h[k] = __floats2half2_rn(Ct[2*k], Ct[2*k+1]);
    *(float4*)(Wc + s1o + (a << 3)) = u.f;
    if (haveGH) {
#pragma unroll
        for (int k = 0; k < 4; ++k) u.h[k] = __floats2half2_rn(G[2*k], G[2*k+1]);
        *(float4*)(GHc + s0o + (a << 3)) = u.f;
#pragma unroll
        for (int k = 0; k < 4; ++k) u.h[k] = __floats2half2_rn(H[2*k], H[2*k+1]);
        *(float4*)(GHc + s1o + (a << 3)) = u.f;
    }
}

// diag (fp16) from CSR-streamed GH: wave per node.
__global__ __launch_bounds__(256) void k_diagS(const int* __restrict__ off,
                                               const __half* __restrict__ GHc,
                                               __half* __restrict__ diag) {
    int wave = (blockIdx.x * blockDim.x + threadIdx.x) >> 6;
    int lane = threadIdx.x & 63;
    int g = lane >> 3, a = lane & 7;
    int m = wave;
    if (m >= M_NODES) return;
    float D[8];
#pragma unroll
    for (int j = 0; j < 8; ++j) D[j] = 0.0f;
    int beg = off[m], end = off[m + 1];
    for (int i = beg + g; i < end; i += 8) {
        union { float4 f; __half2 h[4]; } u;
        u.f = *(const float4*)(GHc + ((size_t)i << 6) + (a << 3));
        float2 w0 = __half22float2(u.h[0]);
        float2 w1 = __half22float2(u.h[1]);
        float2 w2 = __half22float2(u.h[2]);
        float2 w3 = __half22float2(u.h[3]);
        D[0] += w0.x; D[1] += w0.y; D[2] += w1.x; D[3] += w1.y;
        D[4] += w2.x; D[5] += w2.y; D[6] += w3.x; D[7] += w3.y;
    }
#pragma unroll
    for (int j = 0; j < 8; ++j) {
        D[j] += __shfl_xor(D[j], 8, 64);
        D[j] += __shfl_xor(D[j], 16, 64);
        D[j] += __shfl_xor(D[j], 32, 64);
    }
    if (g == 0) {
        D[a] += 1.0f;
        union { float4 f; __half2 h[4]; } u;
#pragma unroll
        for (int k = 0; k < 4; ++k) u.h[k] = __floats2half2_rn(D[2*k], D[2*k+1]);
        *(float4*)(diag + ((size_t)m << 6) + (a << 3)) = u.f;
    }
}

// fallback diag straight from R (runs once)
__global__ void k_diagR(const int* __restrict__ off, const int* __restrict__ wk,
                        const float* __restrict__ Rs, const float* __restrict__ Rd,
                        __half* __restrict__ diag) {
    int gt = blockIdx.x * blockDim.x + threadIdx.x;
    int m = gt >> 3, a = gt & 7;
    if (m >= M_NODES) return;
    float D[8];
#pragma unroll
    for (int j = 0; j < 8; ++j) D[j] = 0.0f;
    int beg = off[m], end = off[m + 1];
    for (int i = beg; i < end; ++i) {
        int k = wk[i];
        int side = (k >= E_EDGES);
        int e = k - (side ? E_EDGES : 0);
        const float* R = (side ? Rd : Rs) + ((size_t)e << 6);
#pragma unroll
        for (int c = 0; c < 8; ++c) {
            float xa = R[c * 8 + a];
            float4 y0 = *(const float4*)(R + c * 8);
            float4 y1 = *(const float4*)(R + c * 8 + 4);
            D[0] += xa * y0.x; D[1] += xa * y0.y; D[2] += xa * y0.z; D[3] += xa * y0.w;
            D[4] += xa * y1.x; D[5] += xa * y1.y; D[6] += xa * y1.z; D[7] += xa * y1.w;
        }
    }
    D[a] += 1.0f;
    union { float4 f; __half2 h[4]; } u;
#pragma unroll
    for (int k = 0; k < 4; ++k) u.h[k] = __floats2half2_rn(D[2*k], D[2*k+1]);
    *(float4*)(diag + ((size_t)m << 6) + (a << 3)) = u.f;
}

// layout convert: orig [b][m][8] -> fp16 interleaved mirror [m][16]
__global__ void k_cvt(const float4* __restrict__ src, __half* __restrict__ ilh) {
    int i = blockIdx.x * blockDim.x + threadIdx.x;
    if (i >= N4) return;
    int b = i / (PER_B / 4);
    int rem = i - b * (PER_B / 4);
    int m = rem >> 1, half = rem & 1;
    int d = (m << 2) + (b << 1) + half;
    writeHalf4(ilh, d, src[i]);
}

// w = A r  (fp16 gather mirror rh). Wave/node grid-strided; incidence loop
// unrolled x2. Fused dot: mu = w.r -> slots.
__global__ __launch_bounds__(256) void k_mv(const __half* __restrict__ rh,
                                            float* __restrict__ wv,
                                            const int* __restrict__ off,
                                            const int* __restrict__ nbA,
                                            const __half* __restrict__ Wc,
                                            const __half* __restrict__ diag,
                                            float* __restrict__ mu) {
    int lane = threadIdx.x & 63;
    int g = lane >> 3, a = lane & 7;
    int waveId = (blockIdx.x * blockDim.x + threadIdx.x) >> 6;
    int nWaves = (gridDim.x * blockDim.x) >> 6;
    float mu0 = 0.f, mu1 = 0.f;
    for (int m = waveId; m < M_NODES; m += nWaves) {
        int beg = off[m], end = off[m + 1];
        float acc0 = 0.f, acc1 = 0.f;
        int i = beg + g;
        for (; i + 8 < end; i += 16) {
            int nA = nbA[i];
            int nB = nbA[i + 8];
            union { float4 f; __half2 h[4]; } uA, uB, rA0, rA1, rB0, rB1;
            uA.f = *(const float4*)(Wc + ((size_t)i << 6) + (a << 3));
            uB.f = *(const float4*)(Wc + ((size_t)(i + 8) << 6) + (a << 3));
            rA0.f = *(const float4*)(rh + (nA << 4));
            rA1.f = *(const float4*)(rh + (nA << 4) + 8);
            rB0.f = *(const float4*)(rh + (nB << 4));
            rB1.f = *(const float4*)(rh + (nB << 4) + 8);
            float2 wA0 = __half22float2(uA.h[0]);
            float2 wA1 = __half22float2(uA.h[1]);
            float2 wA2 = __half22float2(uA.h[2]);
            float2 wA3 = __half22float2(uA.h[3]);
            float2 a00 = __half22float2(rA0.h[0]);
            float2 a01 = __half22float2(rA0.h[1]);
            float2 a02 = __half22float2(rA0.h[2]);
            float2 a03 = __half22float2(rA0.h[3]);
            float2 a10 = __half22float2(rA1.h[0]);
            float2 a11 = __half22float2(rA1.h[1]);
            float2 a12 = __half22float2(rA1.h[2]);
            float2 a13 = __half22float2(rA1.h[3]);
            acc0 += wA0.x*a00.x + wA0.y*a00.y + wA1.x*a01.x + wA1.y*a01.y
                  + wA2.x*a02.x + wA2.y*a02.y + wA3.x*a03.x + wA3.y*a03.y;
            acc1 += wA0.x*a10.x + wA0.y*a10.y + wA1.x*a11.x + wA1.y*a11.y
                  + wA2.x*a12.x + wA2.y*a12.y + wA3.x*a13.x + wA3.y*a13.y;
            float2 wB0 = __half22float2(uB.h[0]);
            float2 wB1 = __half22float2(uB.h[1]);
            float2 wB2 = __half22float2(uB.h[2]);
            float2 wB3 = __half22float2(uB.h[3]);
            float2 b00 = __half22float2(rB0.h[0]);
            float2 b01 = __half22float2(rB0.h[1]);
            float2 b02 = __half22float2(rB0.h[2]);
            float2 b03 = __half22float2(rB0.h[3]);
            float2 b10 = __half22float2(rB1.h[0]);
            float2 b11 = __half22float2(rB1.h[1]);
            float2 b12 = __half22float2(rB1.h[2]);
            float2 b13 = __half22float2(rB1.h[3]);
            acc0 += wB0.x*b00.x + wB0.y*b00.y + wB1.x*b01.x + wB1.y*b01.y
                  + wB2.x*b02.x + wB2.y*b02.y + wB3.x*b03.x + wB3.y*b03.y;
            acc1 += wB0.x*b10.x + wB0.y*b10.y + wB1.x*b11.x + wB1.y*b11.y
                  + wB2.x*b12.x + wB2.y*b12.y + wB3.x*b13.x + wB3.y*b13.y;
        }
        if (i < end) {
            int n = nbA[i];
            union { float4 f; __half2 h[4]; } u, r0, r1;
            u.f = *(const float4*)(Wc + ((size_t)i << 6) + (a << 3));
            r0.f = *(const float4*)(rh + (n << 4));
            r1.f = *(const float4*)(rh + (n << 4) + 8);
            float2 w0 = __half22float2(u.h[0]);
            float2 w1 = __half22float2(u.h[1]);
            float2 w2 = __half22float2(u.h[2]);
            float2 w3 = __half22float2(u.h[3]);
            float2 c00 = __half22float2(r0.h[0]);
            float2 c01 = __half22float2(r0.h[1]);
            float2 c02 = __half22float2(r0.h[2]);
            float2 c03 = __half22float2(r0.h[3]);
            float2 c10 = __half22float2(r1.h[0]);
            float2 c11 = __half22float2(r1.h[1]);
            float2 c12 = __half22float2(r1.h[2]);
            float2 c13 = __half22float2(r1.h[3]);
            acc0 += w0.x*c00.x + w0.y*c00.y + w1.x*c01.x + w1.y*c01.y
                  + w2.x*c02.x + w2.y*c02.y + w3.x*c03.x + w3.y*c03.y;
            acc1 += w0.x*c10.x + w0.y*c10.y + w1.x*c11.x + w1.y*c11.y
                  + w2.x*c12.x + w2.y*c12.y + w3.x*c13.x + w3.y*c13.y;
        }
        acc0 += __shfl_xor(acc0, 8, 64);  acc1 += __shfl_xor(acc1, 8, 64);
        acc0 += __shfl_xor(acc0, 16, 64); acc1 += __shfl_xor(acc1, 16, 64);
        acc0 += __shfl_xor(acc0, 32, 64); acc1 += __shfl_xor(acc1, 32, 64);
        if (g < 2) {
            union { float4 f; __half2 h[4]; } ur, ud;
            ur.f = *(const float4*)(rh + (m << 4) + (g << 3));
            ud.f = *(const float4*)(diag + ((size_t)m << 6) + (a << 3));
            float rm[8];
            float2 t;
            t = __half22float2(ur.h[0]); rm[0] = t.x; rm[1] = t.y;
            t = __half22float2(ur.h[1]); rm[2] = t.x; rm[3] = t.y;
            t = __half22float2(ur.h[2]); rm[4] = t.x; rm[5] = t.y;
            t = __half22float2(ur.h[3]); rm[6] = t.x; rm[7] = t.y;
            float2 g0 = __half22float2(ud.h[0]);
            float2 g1 = __half22float2(ud.h[1]);
            float2 g2 = __half22float2(ud.h[2]);
            float2 g3 = __half22float2(ud.h[3]);
            float acc = g ? acc1 : acc0;
            float w = g0.x*rm[0] + g0.y*rm[1] + g1.x*rm[2] + g1.y*rm[3]
                    + g2.x*rm[4] + g2.y*rm[5] + g3.x*rm[6] + g3.y*rm[7] - acc;
            wv[(m << 4) + (g << 3) + a] = w;
            float ra = rm[a];
            if (g == 0) mu0 += ra * w; else mu1 += ra * w;
        }
    }
    blockReduceAdd2(mu0, mu1, mu);
}

// r = c0perm - w ; x = c0perm ; rh mirror ; rho0 = r.r
__global__ __launch_bounds__(256) void k_init0(const float4* __restrict__ c0,
                                               const float4* __restrict__ w,
                                               float4* __restrict__ r,
                                               __half* __restrict__ rh,
                                               float4* __restrict__ x,
                                               float* __restrict__ rho0) {
    int i = blockIdx.x * blockDim.x + threadIdx.x;
    float s0 = 0.f, s1 = 0.f;
    if (i < N4) {
        int m = i >> 2, slot = i & 3;
        int b = slot >> 1, h = slot & 1;
        float4 bv = c0[b * (PER_B / 4) + (m << 1) + h];
        float4 wv = w[i];
        float4 rv = make_float4(bv.x - wv.x, bv.y - wv.y, bv.z - wv.z, bv.w - wv.w);
        r[i] = rv; x[i] = bv;
        writeHalf4(rh, i, rv);
        float d = rv.x*rv.x + rv.y*rv.y + rv.z*rv.z + rv.w*rv.w;
        int batch = (i >> 1) & 1;
        if (batch == 0) s0 = d; else s1 = d;
    }
    blockReduceAdd2(s0, s1, rho0);
}

// C-G CG update, grid-stride. Scalars once/block (thread 0 -> LDS broadcast).
// p = r + beta p; q = w + beta q; x += alpha p; r -= alpha q (+rh mirror);
// rho_next = r.r. Last iter: write x de-interleaved to out only.
__global__ __launch_bounds__(256) void k_axpy(float4* __restrict__ x,
                                              float4* __restrict__ r,
                                              __half* __restrict__ rh,
                                              float4* __restrict__ p,
                                              float4* __restrict__ q,
                                              const float4* __restrict__ w,
                                              const float* __restrict__ rho_s,
                                              const float* __restrict__ mu_s,
                                              float* __restrict__ fin,
                                              float* __restrict__ rho_next,
                                              int j, int last,
                                              float4* __restrict__ out) {
    __shared__ float sc[4];
    if (threadIdx.x == 0) {
        float2 rho = sumSlots(rho_s);
        float2 mu  = sumSlots(mu_s);
        float b0, b1, al0, al1;
        if (j == 0) {
            b0 = b1 = 0.0f;
            al0 = rho.x / (mu.x + EPSF);
            al1 = rho.y / (mu.y + EPSF);
        } else {
            float ap0 = fin[4*(j-1)+0], ap1 = fin[4*(j-1)+1];
            float rp0 = fin[4*(j-1)+2], rp1 = fin[4*(j-1)+3];
            b0 = rho.x / (rp0 + EPSF);
            b1 = rho.y / (rp1 + EPSF);
            al0 = rho.x / (mu.x - b0 * rho.x / (ap0 + EPSF) + EPSF);
            al1 = rho.y / (mu.y - b1 * rho.y / (ap1 + EPSF) + EPSF);
        }
        if (!last && blockIdx.x == 0) {
            fin[4*j] = al0; fin[4*j+1] = al1; fin[4*j+2] = rho.x; fin[4*j+3] = rho.y;
        }
        sc[0] = al0; sc[1] = al1; sc[2] = b0; sc[3] = b1;
    }
    __syncthreads();
    float al0 = sc[0], al1 = sc[1], b0 = sc[2], b1 = sc[3];
    float s0 = 0.f, s1 = 0.f;
    for (int i = blockIdx.x * blockDim.x + threadIdx.x; i < N4;
         i += gridDim.x * blockDim.x) {
        int batch = (i >> 1) & 1;
        float be = batch ? b1 : b0;
        float al = batch ? al1 : al0;
        float4 rv = r[i], wv = w[i], xv = x[i];
        float4 pn, qn;
        if (j == 0) { pn = rv; qn = wv; }
        else {
            float4 pv = p[i], qv = q[i];
            pn = make_float4(rv.x + be*pv.x, rv.y + be*pv.y, rv.z + be*pv.z, rv.w + be*pv.w);
            qn = make_float4(wv.x + be*qv.x, wv.y + be*qv.y, wv.z + be*qv.z, wv.w + be*qv.w);
        }
        float4 xn = make_float4(xv.x + al*pn.x, xv.y + al*pn.y, xv.z + al*pn.z, xv.w + al*pn.w);
        if (last) {
            int m = i >> 2, slot = i & 3;
            int b = slot >> 1, h = slot & 1;
            out[b * (PER_B / 4) + (m << 1) + h] = xn;
        } else {
            float4 rn = make_float4(rv.x - al*qn.x, rv.y - al*qn.y,
                                    rv.z - al*qn.z, rv.w - al*qn.w);
            x[i] = xn; r[i] = rn; p[i] = pn; q[i] = qn;
            writeHalf4(rh, i, rn);
            float d = rn.x*rn.x + rn.y*rn.y + rn.z*rn.z + rn.w*rn.w;
            if (batch == 0) s0 += d; else s1 += d;
        }
    }
    if (!last) blockReduceAdd2(s0, s1, rho_next);
}

extern "C" void kernel_launch(void* const* d_in, const int* in_sizes, int n_in,
                              void* d_out, int out_size, void* d_ws, size_t ws_size,
                              hipStream_t stream) {
    const float* c0 = (const float*)d_in[0];
    const int* src  = (const int*)d_in[1];
    const int* dst  = (const int*)d_in[2];
    const float* Rs = (const float*)d_in[3];
    const float* Rd = (const float*)d_in[4];

    char* wsp = (char*)d_ws;
    size_t o = 0;
    auto alloc = [&](size_t bytes) { char* c = wsp + o; o = (o + bytes + 255) & ~(size_t)255; return c; };
    float* r      = (float*)alloc(VEC_N * 4);
    float* wv     = (float*)alloc(VEC_N * 4);
    float* p      = (float*)alloc(VEC_N * 4);
    float* q      = (float*)alloc(VEC_N * 4);
    float* x      = (float*)alloc(VEC_N * 4);
    __half* rh    = (__half*)alloc(VEC_N * 2);
    __half* bh    = (__half*)alloc(VEC_N * 2);
    float* scal   = (float*)alloc(4096 * 4);
    int*   cnt    = (int*)alloc(M_NODES * 4);
    int*   offa   = (int*)alloc((M_NODES + 1) * 4);
    int*   cursor = (int*)alloc(M_NODES * 4);
    int*   pos0   = (int*)alloc(E_EDGES * 4);
    int*   pos1   = (int*)alloc(E_EDGES * 4);
    int*   wk     = (int*)alloc(N_INC * 4);
    int*   nb     = (int*)alloc(N_INC * 4);
    __half* diag  = (__half*)alloc((size_t)M_NODES * 64 * 2);
    __half* Wc    = (__half*)alloc((size_t)N_INC * 64 * 2);
    size_t ghBytes = (size_t)N_INC * 64 * 2;
    int haveGH = (o + ghBytes) <= ws_size;
    __half* GHc = haveGH ? (__half*)alloc(ghBytes) : (__half*)Wc;

    const int BLK = 256;
    const int grid_v  = (N4 + BLK - 1) / BLK;
    const int grid_e  = (E_EDGES + BLK - 1) / BLK;
    const int grid_m  = (M_NODES + BLK - 1) / BLK;
    const int grid_e8 = (E_EDGES * 8 + BLK - 1) / BLK;
    const int grid_m8 = (M_NODES * 8 + BLK - 1) / BLK;
    const int grid_mw = (M_NODES * 64 + BLK - 1) / BLK;
    const int MVB     = 2048;
    const int AXB     = 512;

    float* RHO = scal;             // RHO(t) = scal + 64*t
    float* MU  = scal + 1024;      // MU(t)  = scal + 1024 + 64*t
    float* FIN = scal + 3968;

    // ---- precompute (rebuilt every call) ----
    k_zero<<<grid_m, BLK, 0, stream>>>(scal, cnt);
    k_hist<<<grid_e, BLK, 0, stream>>>(src, dst, cnt);
    k_scan<<<1, SCAN_T, 0, stream>>>(cnt, offa, cursor);
    k_scatter<<<grid_e, BLK, 0, stream>>>(src, dst, cursor, pos0, pos1, nb, wk);
    k_buildC<<<grid_e8, BLK, 0, stream>>>(Rs, Rd, pos0, pos1, Wc, GHc, haveGH);
    if (haveGH)
        k_diagS<<<grid_mw, BLK, 0, stream>>>(offa, GHc, diag);
    else
        k_diagR<<<grid_m8, BLK, 0, stream>>>(offa, wk, Rs, Rd, diag);

    // ---- init: bh = fp16(interleave(c0)); w = A b; r = b - w; x = b; rho0 ----
    k_cvt<<<grid_v, BLK, 0, stream>>>((const float4*)c0, bh);
    k_mv<<<MVB, BLK, 0, stream>>>(bh, wv, offa, nb, Wc, diag, MU + 64 * 12);
    k_init0<<<grid_v, BLK, 0, stream>>>((const float4*)c0, (const float4*)wv,
                                        (float4*)r, rh, (float4*)x, RHO);

    // ---- C-G CG: 2 kernels/iter, matvec on rh ----
    for (int t = 0; t < CG_ITERS; ++t) {
        k_mv<<<MVB, BLK, 0, stream>>>(rh, wv, offa, nb, Wc, diag, MU + 64 * t);
        k_axpy<<<AXB, BLK, 0, stream>>>((float4*)x, (float4*)r, rh, (float4*)p,
                                        (float4*)q, (const float4*)wv,
                                        RHO + 64 * t, MU + 64 * t, FIN,
                                        RHO + 64 * (t + 1), t,
                                        (t == CG_ITERS - 1) ? 1 : 0,
                                        (float4*)d_out);
    }
}

// Round 14
// 840.686 us; speedup vs baseline: 2.9683x; 1.2611x over previous
//
#include <hip/hip_runtime.h>
#include <hip/hip_fp16.h>

#define E_EDGES   400000
#define M_NODES   50000
#define N_INC     800000
#define PER_B     400000
#define VEC_N     800000
#define N4        200000
#define CG_ITERS  9
#define EPSF      1e-12f

// scal (4096 floats): 32 slot-pairs (64 floats) per instance.
//   RHO(t) = scal + 64*t           t=0..12
//   MU(t)  = scal + 1024 + 64*t    t=0..12  (t=12 = init-mv scratch)
//   fin    = scal + 3968 : fin[4t+0/1]=alpha_t(b0/b1), fin[4t+2/3]=rho_t(b0/b1)

__device__ __forceinline__ float waveReduce(float v) {
#pragma unroll
    for (int off = 32; off > 0; off >>= 1)
        v += __shfl_down(v, off, 64);
    return v;
}

__device__ __forceinline__ void blockReduceAdd2(float d0, float d1, float* __restrict__ base) {
    __shared__ float red[8];
    d0 = waveReduce(d0);
    d1 = waveReduce(d1);
    int w = threadIdx.x >> 6, lane = threadIdx.x & 63;
    if (lane == 0) { red[2*w] = d0; red[2*w+1] = d1; }
    __syncthreads();
    if (threadIdx.x == 0) {
        float t0 = red[0] + red[2] + red[4] + red[6];
        float t1 = red[1] + red[3] + red[5] + red[7];
        int s = (blockIdx.x & 31) << 1;
        atomicAdd(&base[s], t0);
        atomicAdd(&base[s + 1], t1);
    }
}

__device__ __forceinline__ float2 sumSlots(const float* __restrict__ base) {
    float a = 0.0f, b = 0.0f;
#pragma unroll
    for (int k = 0; k < 32; ++k) { a += base[2*k]; b += base[2*k+1]; }
    return make_float2(a, b);
}

__device__ __forceinline__ void writeHalf4(__half* __restrict__ rh, int i4, float4 v) {
    union { float2 f2; __half2 h[2]; } u;
    u.h[0] = __floats2half2_rn(v.x, v.y);
    u.h[1] = __floats2half2_rn(v.z, v.w);
    *(float2*)(rh + (i4 << 2)) = u.f2;
}

// zero scal (4096 floats) + cnt (M_NODES ints) in one launch
__global__ void k_zero(float* __restrict__ s, int* __restrict__ cnt) {
    int i = blockIdx.x * blockDim.x + threadIdx.x;
    if (i < 4096) s[i] = 0.0f;
    if (i < M_NODES) cnt[i] = 0;
}

__global__ void k_hist(const int* __restrict__ src, const int* __restrict__ dst,
                       int* __restrict__ cnt) {
    int e = blockIdx.x * blockDim.x + threadIdx.x;
    if (e < E_EDGES) {
        atomicAdd(&cnt[src[e]], 1);
        atomicAdd(&cnt[dst[e]], 1);
    }
}

// ---- multi-block exclusive scan of cnt[M_NODES] -> off[0..M], cursor ----
#define SCT 256
#define SCB ((M_NODES + SCT - 1) / SCT)   // 196

// phase A: per-block exclusive scan (coalesced); btot = block total
__global__ __launch_bounds__(SCT) void k_scanA(const int* __restrict__ cnt,
                                               int* __restrict__ partial,
                                               int* __restrict__ btot) {
    __shared__ int sh[SCT];
    int i = blockIdx.x * SCT + threadIdx.x;
    int v = (i < M_NODES) ? cnt[i] : 0;
    sh[threadIdx.x] = v;
    __syncthreads();
    for (int st = 1; st < SCT; st <<= 1) {
        int t = (threadIdx.x >= st) ? sh[threadIdx.x - st] : 0;
        __syncthreads();
        sh[threadIdx.x] += t;
        __syncthreads();
    }
    if (i < M_NODES) partial[i] = sh[threadIdx.x] - v;   // exclusive
    if (threadIdx.x == SCT - 1) btot[blockIdx.x] = sh[SCT - 1];
}

// phase B: single block scans SCB block totals -> boff (exclusive); writes off[M]
__global__ __launch_bounds__(SCT) void k_scanB(const int* __restrict__ btot,
                                               int* __restrict__ boff,
                                               int* __restrict__ off) {
    __shared__ int sh[SCT];
    int v = (threadIdx.x < SCB) ? btot[threadIdx.x] : 0;
    sh[threadIdx.x] = v;
    __syncthreads();
    for (int st = 1; st < SCT; st <<= 1) {
        int t = (threadIdx.x >= st) ? sh[threadIdx.x - st] : 0;
        __syncthreads();
        sh[threadIdx.x] += t;
        __syncthreads();
    }
    if (threadIdx.x < SCB) boff[threadIdx.x] = sh[threadIdx.x] - v;
    if (threadIdx.x == SCT - 1) off[M_NODES] = sh[SCT - 1];
}

// phase C: off[i] = boff[blk] + partial[i]; cursor copy
__global__ __launch_bounds__(SCT) void k_scanC(const int* __restrict__ partial,
                                               const int* __restrict__ boff,
                                               int* __restrict__ off,
                                               int* __restrict__ cursor) {
    int i = blockIdx.x * SCT + threadIdx.x;
    if (i < M_NODES) {
        int o = boff[blockIdx.x] + partial[i];
        off[i] = o; cursor[i] = o;
    }
}

__global__ void k_scatter(const int* __restrict__ src, const int* __restrict__ dst,
                          int* __restrict__ cursor, int* __restrict__ pos0,
                          int* __restrict__ pos1, int* __restrict__ nb,
                          int* __restrict__ wk) {
    int e = blockIdx.x * blockDim.x + threadIdx.x;
    if (e < E_EDGES) {
        int s = src[e], t = dst[e];
        int p0 = atomicAdd(&cursor[s], 1);
        pos0[e] = p0; nb[p0] = t; wk[p0] = e;
        int p1 = atomicAdd(&cursor[t], 1);
        pos1[e] = p1; nb[p1] = s; wk[p1] = e + E_EDGES;
    }
}

// 8 lanes/edge, coalesced sequential R reads; scatter-write 128B blocks to CSR slots.
__global__ __launch_bounds__(256) void k_buildC(const float* __restrict__ Rs,
                                                const float* __restrict__ Rd,
                                                const int* __restrict__ pos0,
                                                const int* __restrict__ pos1,
                                                __half* __restrict__ Wc,
                                                __half* __restrict__ GHc, int haveGH) {
    int gt = blockIdx.x * blockDim.x + threadIdx.x;
    int e = gt >> 3, a = gt & 7;
    if (e >= E_EDGES) return;
    const float* rs = Rs + ((size_t)e << 6);
    const float* rd = Rd + ((size_t)e << 6);
    float C[8], Ct[8], G[8], H[8];
#pragma unroll
    for (int j = 0; j < 8; ++j) { C[j] = 0; Ct[j] = 0; G[j] = 0; H[j] = 0; }
#pragma unroll
    for (int c = 0; c < 8; ++c) {
        float xs = rs[c * 8 + a];
        float xd = rd[c * 8 + a];
        float4 s0 = *(const float4*)(rs + c * 8);
        float4 s1 = *(const float4*)(rs + c * 8 + 4);
        float4 d0 = *(const float4*)(rd + c * 8);
        float4 d1 = *(const float4*)(rd + c * 8 + 4);
        C[0] += xs * d0.x; C[1] += xs * d0.y; C[2] += xs * d0.z; C[3] += xs * d0.w;
        C[4] += xs * d1.x; C[5] += xs * d1.y; C[6] += xs * d1.z; C[7] += xs * d1.w;
        Ct[0] += xd * s0.x; Ct[1] += xd * s0.y; Ct[2] += xd * s0.z; Ct[3] += xd * s0.w;
        Ct[4] += xd * s1.x; Ct[5] += xd * s1.y; Ct[6] += xd * s1.z; Ct[7] += xd * s1.w;
        G[0] += xs * s0.x; G[1] += xs * s0.y; G[2] += xs * s0.z; G[3] += xs * s0.w;
        G[4] += xs * s1.x; G[5] += xs * s1.y; G[6] += xs * s1.z; G[7] += xs * s1.w;
        H[0] += xd * d0.x; H[1] += xd * d0.y; H[2] += xd * d0.z; H[3] += xd * d0.w;
        H[4] += xd * d1.x; H[5] += xd * d1.y; H[6] += xd * d1.z; H[7] += xd * d1.w;
    }
    size_t s0o = (size_t)pos0[e] << 6;
    size_t s1o = (size_t)pos1[e] << 6;
    union { float4 f; __half2 h[4]; } u;
#pragma unroll
    for (int k = 0; k < 4; ++k) u.h[k] = __floats2half2_rn(C[2*k], C[2*k+1]);
    *(float4*)(Wc + s0o + (a << 3)) = u.f;
#pragma unroll
    for (int k = 0; k < 4; ++k) u.h[k] = __floats2half2_rn(Ct[2*k], Ct[2*k+1]);
    *(float4*)(Wc + s1o + (a << 3)) = u.f;
    if (haveGH) {
#pragma unroll
        for (int k = 0; k < 4; ++k) u.h[k] = __floats2half2_rn(G[2*k], G[2*k+1]);
        *(float4*)(GHc + s0o + (a << 3)) = u.f;
#pragma unroll
        for (int k = 0; k < 4; ++k) u.h[k] = __floats2half2_rn(H[2*k], H[2*k+1]);
        *(float4*)(GHc + s1o + (a << 3)) = u.f;
    }
}

// diag (fp16) from CSR-streamed GH: wave per node.
__global__ __launch_bounds__(256) void k_diagS(const int* __restrict__ off,
                                               const __half* __restrict__ GHc,
                                               __half* __restrict__ diag) {
    int wave = (blockIdx.x * blockDim.x + threadIdx.x) >> 6;
    int lane = threadIdx.x & 63;
    int g = lane >> 3, a = lane & 7;
    int m = wave;
    if (m >= M_NODES) return;
    float D[8];
#pragma unroll
    for (int j = 0; j < 8; ++j) D[j] = 0.0f;
    int beg = off[m], end = off[m + 1];
    for (int i = beg + g; i < end; i += 8) {
        union { float4 f; __half2 h[4]; } u;
        u.f = *(const float4*)(GHc + ((size_t)i << 6) + (a << 3));
        float2 w0 = __half22float2(u.h[0]);
        float2 w1 = __half22float2(u.h[1]);
        float2 w2 = __half22float2(u.h[2]);
        float2 w3 = __half22float2(u.h[3]);
        D[0] += w0.x; D[1] += w0.y; D[2] += w1.x; D[3] += w1.y;
        D[4] += w2.x; D[5] += w2.y; D[6] += w3.x; D[7] += w3.y;
    }
#pragma unroll
    for (int j = 0; j < 8; ++j) {
        D[j] += __shfl_xor(D[j], 8, 64);
        D[j] += __shfl_xor(D[j], 16, 64);
        D[j] += __shfl_xor(D[j], 32, 64);
    }
    if (g == 0) {
        D[a] += 1.0f;
        union { float4 f; __half2 h[4]; } u;
#pragma unroll
        for (int k = 0; k < 4; ++k) u.h[k] = __floats2half2_rn(D[2*k], D[2*k+1]);
        *(float4*)(diag + ((size_t)m << 6) + (a << 3)) = u.f;
    }
}

// fallback diag straight from R (runs once)
__global__ void k_diagR(const int* __restrict__ off, const int* __restrict__ wk,
                        const float* __restrict__ Rs, const float* __restrict__ Rd,
                        __half* __restrict__ diag) {
    int gt = blockIdx.x * blockDim.x + threadIdx.x;
    int m = gt >> 3, a = gt & 7;
    if (m >= M_NODES) return;
    float D[8];
#pragma unroll
    for (int j = 0; j < 8; ++j) D[j] = 0.0f;
    int beg = off[m], end = off[m + 1];
    for (int i = beg; i < end; ++i) {
        int k = wk[i];
        int side = (k >= E_EDGES);
        int e = k - (side ? E_EDGES : 0);
        const float* R = (side ? Rd : Rs) + ((size_t)e << 6);
#pragma unroll
        for (int c = 0; c < 8; ++c) {
            float xa = R[c * 8 + a];
            float4 y0 = *(const float4*)(R + c * 8);
            float4 y1 = *(const float4*)(R + c * 8 + 4);
            D[0] += xa * y0.x; D[1] += xa * y0.y; D[2] += xa * y0.z; D[3] += xa * y0.w;
            D[4] += xa * y1.x; D[5] += xa * y1.y; D[6] += xa * y1.z; D[7] += xa * y1.w;
        }
    }
    D[a] += 1.0f;
    union { float4 f; __half2 h[4]; } u;
#pragma unroll
    for (int k = 0; k < 4; ++k) u.h[k] = __floats2half2_rn(D[2*k], D[2*k+1]);
    *(float4*)(diag + ((size_t)m << 6) + (a << 3)) = u.f;
}

// layout convert: orig [b][m][8] -> fp16 interleaved mirror [m][16]
__global__ void k_cvt(const float4* __restrict__ src, __half* __restrict__ ilh) {
    int i = blockIdx.x * blockDim.x + threadIdx.x;
    if (i >= N4) return;
    int b = i / (PER_B / 4);
    int rem = i - b * (PER_B / 4);
    int m = rem >> 1, half = rem & 1;
    int d = (m << 2) + (b << 1) + half;
    writeHalf4(ilh, d, src[i]);
}

// w = A r  (fp16 gather mirror rh). Wave/node grid-strided; incidence loop
// unrolled x2. Fused dot: mu = w.r -> slots.
__global__ __launch_bounds__(256) void k_mv(const __half* __restrict__ rh,
                                            float* __restrict__ wv,
                                            const int* __restrict__ off,
                                            const int* __restrict__ nbA,
                                            const __half* __restrict__ Wc,
                                            const __half* __restrict__ diag,
                                            float* __restrict__ mu) {
    int lane = threadIdx.x & 63;
    int g = lane >> 3, a = lane & 7;
    int waveId = (blockIdx.x * blockDim.x + threadIdx.x) >> 6;
    int nWaves = (gridDim.x * blockDim.x) >> 6;
    float mu0 = 0.f, mu1 = 0.f;
    for (int m = waveId; m < M_NODES; m += nWaves) {
        int beg = off[m], end = off[m + 1];
        float acc0 = 0.f, acc1 = 0.f;
        int i = beg + g;
        for (; i + 8 < end; i += 16) {
            int nA = nbA[i];
            int nB = nbA[i + 8];
            union { float4 f; __half2 h[4]; } uA, uB, rA0, rA1, rB0, rB1;
            uA.f = *(const float4*)(Wc + ((size_t)i << 6) + (a << 3));
            uB.f = *(const float4*)(Wc + ((size_t)(i + 8) << 6) + (a << 3));
            rA0.f = *(const float4*)(rh + (nA << 4));
            rA1.f = *(const float4*)(rh + (nA << 4) + 8);
            rB0.f = *(const float4*)(rh + (nB << 4));
            rB1.f = *(const float4*)(rh + (nB << 4) + 8);
            float2 wA0 = __half22float2(uA.h[0]);
            float2 wA1 = __half22float2(uA.h[1]);
            float2 wA2 = __half22float2(uA.h[2]);
            float2 wA3 = __half22float2(uA.h[3]);
            float2 a00 = __half22float2(rA0.h[0]);
            float2 a01 = __half22float2(rA0.h[1]);
            float2 a02 = __half22float2(rA0.h[2]);
            float2 a03 = __half22float2(rA0.h[3]);
            float2 a10 = __half22float2(rA1.h[0]);
            float2 a11 = __half22float2(rA1.h[1]);
            float2 a12 = __half22float2(rA1.h[2]);
            float2 a13 = __half22float2(rA1.h[3]);
            acc0 += wA0.x*a00.x + wA0.y*a00.y + wA1.x*a01.x + wA1.y*a01.y
                  + wA2.x*a02.x + wA2.y*a02.y + wA3.x*a03.x + wA3.y*a03.y;
            acc1 += wA0.x*a10.x + wA0.y*a10.y + wA1.x*a11.x + wA1.y*a11.y
                  + wA2.x*a12.x + wA2.y*a12.y + wA3.x*a13.x + wA3.y*a13.y;
            float2 wB0 = __half22float2(uB.h[0]);
            float2 wB1 = __half22float2(uB.h[1]);
            float2 wB2 = __half22float2(uB.h[2]);
            float2 wB3 = __half22float2(uB.h[3]);
            float2 b00 = __half22float2(rB0.h[0]);
            float2 b01 = __half22float2(rB0.h[1]);
            float2 b02 = __half22float2(rB0.h[2]);
            float2 b03 = __half22float2(rB0.h[3]);
            float2 b10 = __half22float2(rB1.h[0]);
            float2 b11 = __half22float2(rB1.h[1]);
            float2 b12 = __half22float2(rB1.h[2]);
            float2 b13 = __half22float2(rB1.h[3]);
            acc0 += wB0.x*b00.x + wB0.y*b00.y + wB1.x*b01.x + wB1.y*b01.y
                  + wB2.x*b02.x + wB2.y*b02.y + wB3.x*b03.x + wB3.y*b03.y;
            acc1 += wB0.x*b10.x + wB0.y*b10.y + wB1.x*b11.x + wB1.y*b11.y
                  + wB2.x*b12.x + wB2.y*b12.y + wB3.x*b13.x + wB3.y*b13.y;
        }
        if (i < end) {
            int n = nbA[i];
            union { float4 f; __half2 h[4]; } u, r0, r1;
            u.f = *(const float4*)(Wc + ((size_t)i << 6) + (a << 3));
            r0.f = *(const float4*)(rh + (n << 4));
            r1.f = *(const float4*)(rh + (n << 4) + 8);
            float2 w0 = __half22float2(u.h[0]);
            float2 w1 = __half22float2(u.h[1]);
            float2 w2 = __half22float2(u.h[2]);
            float2 w3 = __half22float2(u.h[3]);
            float2 c00 = __half22float2(r0.h[0]);
            float2 c01 = __half22float2(r0.h[1]);
            float2 c02 = __half22float2(r0.h[2]);
            float2 c03 = __half22float2(r0.h[3]);
            float2 c10 = __half22float2(r1.h[0]);
            float2 c11 = __half22float2(r1.h[1]);
            float2 c12 = __half22float2(r1.h[2]);
            float2 c13 = __half22float2(r1.h[3]);
            acc0 += w0.x*c00.x + w0.y*c00.y + w1.x*c01.x + w1.y*c01.y
                  + w2.x*c02.x + w2.y*c02.y + w3.x*c03.x + w3.y*c03.y;
            acc1 += w0.x*c10.x + w0.y*c10.y + w1.x*c11.x + w1.y*c11.y
                  + w2.x*c12.x + w2.y*c12.y + w3.x*c13.x + w3.y*c13.y;
        }
        acc0 += __shfl_xor(acc0, 8, 64);  acc1 += __shfl_xor(acc1, 8, 64);
        acc0 += __shfl_xor(acc0, 16, 64); acc1 += __shfl_xor(acc1, 16, 64);
        acc0 += __shfl_xor(acc0, 32, 64); acc1 += __shfl_xor(acc1, 32, 64);
        if (g < 2) {
            union { float4 f; __half2 h[4]; } ur, ud;
            ur.f = *(const float4*)(rh + (m << 4) + (g << 3));
            ud.f = *(const float4*)(diag + ((size_t)m << 6) + (a << 3));
            float rm[8];
            float2 t;
            t = __half22float2(ur.h[0]); rm[0] = t.x; rm[1] = t.y;
            t = __half22float2(ur.h[1]); rm[2] = t.x; rm[3] = t.y;
            t = __half22float2(ur.h[2]); rm[4] = t.x; rm[5] = t.y;
            t = __half22float2(ur.h[3]); rm[6] = t.x; rm[7] = t.y;
            float2 g0 = __half22float2(ud.h[0]);
            float2 g1 = __half22float2(ud.h[1]);
            float2 g2 = __half22float2(ud.h[2]);
            float2 g3 = __half22float2(ud.h[3]);
            float acc = g ? acc1 : acc0;
            float w = g0.x*rm[0] + g0.y*rm[1] + g1.x*rm[2] + g1.y*rm[3]
                    + g2.x*rm[4] + g2.y*rm[5] + g3.x*rm[6] + g3.y*rm[7] - acc;
            wv[(m << 4) + (g << 3) + a] = w;
            float ra = rm[a];
            if (g == 0) mu0 += ra * w; else mu1 += ra * w;
        }
    }
    blockReduceAdd2(mu0, mu1, mu);
}

// r = c0perm - w ; x = c0perm ; rh mirror ; rho0 = r.r
__global__ __launch_bounds__(256) void k_init0(const float4* __restrict__ c0,
                                               const float4* __restrict__ w,
                                               float4* __restrict__ r,
                                               __half* __restrict__ rh,
                                               float4* __restrict__ x,
                                               float* __restrict__ rho0) {
    int i = blockIdx.x * blockDim.x + threadIdx.x;
    float s0 = 0.f, s1 = 0.f;
    if (i < N4) {
        int m = i >> 2, slot = i & 3;
        int b = slot >> 1, h = slot & 1;
        float4 bv = c0[b * (PER_B / 4) + (m << 1) + h];
        float4 wv = w[i];
        float4 rv = make_float4(bv.x - wv.x, bv.y - wv.y, bv.z - wv.z, bv.w - wv.w);
        r[i] = rv; x[i] = bv;
        writeHalf4(rh, i, rv);
        float d = rv.x*rv.x + rv.y*rv.y + rv.z*rv.z + rv.w*rv.w;
        int batch = (i >> 1) & 1;
        if (batch == 0) s0 = d; else s1 = d;
    }
    blockReduceAdd2(s0, s1, rho0);
}

// C-G CG update, grid-stride. Scalars once/block (thread 0 -> LDS broadcast).
// p = r + beta p; q = w + beta q; x += alpha p; r -= alpha q (+rh mirror);
// rho_next = r.r. Last iter: write x de-interleaved to out only.
__global__ __launch_bounds__(256) void k_axpy(float4* __restrict__ x,
                                              float4* __restrict__ r,
                                              __half* __restrict__ rh,
                                              float4* __restrict__ p,
                                              float4* __restrict__ q,
                                              const float4* __restrict__ w,
                                              const float* __restrict__ rho_s,
                                              const float* __restrict__ mu_s,
                                              float* __restrict__ fin,
                                              float* __restrict__ rho_next,
                                              int j, int last,
                                              float4* __restrict__ out) {
    __shared__ float sc[4];
    if (threadIdx.x == 0) {
        float2 rho = sumSlots(rho_s);
        float2 mu  = sumSlots(mu_s);
        float b0, b1, al0, al1;
        if (j == 0) {
            b0 = b1 = 0.0f;
            al0 = rho.x / (mu.x + EPSF);
            al1 = rho.y / (mu.y + EPSF);
        } else {
            float ap0 = fin[4*(j-1)+0], ap1 = fin[4*(j-1)+1];
            float rp0 = fin[4*(j-1)+2], rp1 = fin[4*(j-1)+3];
            b0 = rho.x / (rp0 + EPSF);
            b1 = rho.y / (rp1 + EPSF);
            al0 = rho.x / (mu.x - b0 * rho.x / (ap0 + EPSF) + EPSF);
            al1 = rho.y / (mu.y - b1 * rho.y / (ap1 + EPSF) + EPSF);
        }
        if (!last && blockIdx.x == 0) {
            fin[4*j] = al0; fin[4*j+1] = al1; fin[4*j+2] = rho.x; fin[4*j+3] = rho.y;
        }
        sc[0] = al0; sc[1] = al1; sc[2] = b0; sc[3] = b1;
    }
    __syncthreads();
    float al0 = sc[0], al1 = sc[1], b0 = sc[2], b1 = sc[3];
    float s0 = 0.f, s1 = 0.f;
    for (int i = blockIdx.x * blockDim.x + threadIdx.x; i < N4;
         i += gridDim.x * blockDim.x) {
        int batch = (i >> 1) & 1;
        float be = batch ? b1 : b0;
        float al = batch ? al1 : al0;
        float4 rv = r[i], wv = w[i], xv = x[i];
        float4 pn, qn;
        if (j == 0) { pn = rv; qn = wv; }
        else {
            float4 pv = p[i], qv = q[i];
            pn = make_float4(rv.x + be*pv.x, rv.y + be*pv.y, rv.z + be*pv.z, rv.w + be*pv.w);
            qn = make_float4(wv.x + be*qv.x, wv.y + be*qv.y, wv.z + be*qv.z, wv.w + be*qv.w);
        }
        float4 xn = make_float4(xv.x + al*pn.x, xv.y + al*pn.y, xv.z + al*pn.z, xv.w + al*pn.w);
        if (last) {
            int m = i >> 2, slot = i & 3;
            int b = slot >> 1, h = slot & 1;
            out[b * (PER_B / 4) + (m << 1) + h] = xn;
        } else {
            float4 rn = make_float4(rv.x - al*qn.x, rv.y - al*qn.y,
                                    rv.z - al*qn.z, rv.w - al*qn.w);
            x[i] = xn; r[i] = rn; p[i] = pn; q[i] = qn;
            writeHalf4(rh, i, rn);
            float d = rn.x*rn.x + rn.y*rn.y + rn.z*rn.z + rn.w*rn.w;
            if (batch == 0) s0 += d; else s1 += d;
        }
    }
    if (!last) blockReduceAdd2(s0, s1, rho_next);
}

extern "C" void kernel_launch(void* const* d_in, const int* in_sizes, int n_in,
                              void* d_out, int out_size, void* d_ws, size_t ws_size,
                              hipStream_t stream) {
    const float* c0 = (const float*)d_in[0];
    const int* src  = (const int*)d_in[1];
    const int* dst  = (const int*)d_in[2];
    const float* Rs = (const float*)d_in[3];
    const float* Rd = (const float*)d_in[4];

    char* wsp = (char*)d_ws;
    size_t o = 0;
    auto alloc = [&](size_t bytes) { char* c = wsp + o; o = (o + bytes + 255) & ~(size_t)255; return c; };
    float* r      = (float*)alloc(VEC_N * 4);
    float* wv     = (float*)alloc(VEC_N * 4);
    float* p      = (float*)alloc(VEC_N * 4);
    float* q      = (float*)alloc(VEC_N * 4);
    float* x      = (float*)alloc(VEC_N * 4);
    __half* rh    = (__half*)alloc(VEC_N * 2);
    __half* bh    = (__half*)alloc(VEC_N * 2);
    float* scal   = (float*)alloc(4096 * 4);
    int*   cnt    = (int*)alloc(M_NODES * 4);
    int*   offa   = (int*)alloc((M_NODES + 1) * 4);
    int*   cursor = (int*)alloc(M_NODES * 4);
    int*   partial= (int*)alloc(M_NODES * 4);
    int*   btot   = (int*)alloc(SCB * 4);
    int*   boff   = (int*)alloc(SCB * 4);
    int*   pos0   = (int*)alloc(E_EDGES * 4);
    int*   pos1   = (int*)alloc(E_EDGES * 4);
    int*   wk     = (int*)alloc(N_INC * 4);
    int*   nb     = (int*)alloc(N_INC * 4);
    __half* diag  = (__half*)alloc((size_t)M_NODES * 64 * 2);
    __half* Wc    = (__half*)alloc((size_t)N_INC * 64 * 2);
    size_t ghBytes = (size_t)N_INC * 64 * 2;
    int haveGH = (o + ghBytes) <= ws_size;
    __half* GHc = haveGH ? (__half*)alloc(ghBytes) : (__half*)Wc;

    const int BLK = 256;
    const int grid_v  = (N4 + BLK - 1) / BLK;
    const int grid_e  = (E_EDGES + BLK - 1) / BLK;
    const int grid_m  = (M_NODES + BLK - 1) / BLK;
    const int grid_e8 = (E_EDGES * 8 + BLK - 1) / BLK;
    const int grid_m8 = (M_NODES * 8 + BLK - 1) / BLK;
    const int grid_mw = (M_NODES * 64 + BLK - 1) / BLK;
    const int MVB     = 2048;
    const int AXB     = 512;

    float* RHO = scal;             // RHO(t) = scal + 64*t
    float* MU  = scal + 1024;      // MU(t)  = scal + 1024 + 64*t
    float* FIN = scal + 3968;

    // ---- precompute (rebuilt every call) ----
    k_zero<<<grid_m, BLK, 0, stream>>>(scal, cnt);
    k_hist<<<grid_e, BLK, 0, stream>>>(src, dst, cnt);
    k_scanA<<<SCB, SCT, 0, stream>>>(cnt, partial, btot);
    k_scanB<<<1, SCT, 0, stream>>>(btot, boff, offa);
    k_scanC<<<SCB, SCT, 0, stream>>>(partial, boff, offa, cursor);
    k_scatter<<<grid_e, BLK, 0, stream>>>(src, dst, cursor, pos0, pos1, nb, wk);
    k_buildC<<<grid_e8, BLK, 0, stream>>>(Rs, Rd, pos0, pos1, Wc, GHc, haveGH);
    if (haveGH)
        k_diagS<<<grid_mw, BLK, 0, stream>>>(offa, GHc, diag);
    else
        k_diagR<<<grid_m8, BLK, 0, stream>>>(offa, wk, Rs, Rd, diag);

    // ---- init: bh = fp16(interleave(c0)); w = A b; r = b - w; x = b; rho0 ----
    k_cvt<<<grid_v, BLK, 0, stream>>>((const float4*)c0, bh);
    k_mv<<<MVB, BLK, 0, stream>>>(bh, wv, offa, nb, Wc, diag, MU + 64 * 12);
    k_init0<<<grid_v, BLK, 0, stream>>>((const float4*)c0, (const float4*)wv,
                                        (float4*)r, rh, (float4*)x, RHO);

    // ---- C-G CG: 2 kernels/iter, matvec on rh ----
    for (int t = 0; t < CG_ITERS; ++t) {
        k_mv<<<MVB, BLK, 0, stream>>>(rh, wv, offa, nb, Wc, diag, MU + 64 * t);
        k_axpy<<<AXB, BLK, 0, stream>>>((float4*)x, (float4*)r, rh, (float4*)p,
                                        (float4*)q, (const float4*)wv,
                                        RHO + 64 * t, MU + 64 * t, FIN,
                                        RHO + 64 * (t + 1), t,
                                        (t == CG_ITERS - 1) ? 1 : 0,
                                        (float4*)d_out);
    }
}

// Round 15
// 667.330 us; speedup vs baseline: 3.7394x; 1.2598x over previous
//
#include <hip/hip_runtime.h>
#include <hip/hip_fp16.h>

#define E_EDGES   400000
#define M_NODES   50000
#define N_INC     800000
#define PER_B     400000
#define VEC_N     800000
#define N4        200000
#define CG_ITERS  6
#define EPSF      1e-12f

// scal (4096 floats): 32 slot-pairs (64 floats) per instance.
//   RHO(t) = scal + 64*t           t=0..12
//   MU(t)  = scal + 1024 + 64*t    t=0..12  (t=12 = init-mv scratch)
//   fin    = scal + 3968 : fin[4t+0/1]=alpha_t(b0/b1), fin[4t+2/3]=rho_t(b0/b1)

__device__ __forceinline__ float waveReduce(float v) {
#pragma unroll
    for (int off = 32; off > 0; off >>= 1)
        v += __shfl_down(v, off, 64);
    return v;
}

__device__ __forceinline__ void blockReduceAdd2(float d0, float d1, float* __restrict__ base) {
    __shared__ float red[8];
    d0 = waveReduce(d0);
    d1 = waveReduce(d1);
    int w = threadIdx.x >> 6, lane = threadIdx.x & 63;
    if (lane == 0) { red[2*w] = d0; red[2*w+1] = d1; }
    __syncthreads();
    if (threadIdx.x == 0) {
        float t0 = red[0] + red[2] + red[4] + red[6];
        float t1 = red[1] + red[3] + red[5] + red[7];
        int s = (blockIdx.x & 31) << 1;
        atomicAdd(&base[s], t0);
        atomicAdd(&base[s + 1], t1);
    }
}

__device__ __forceinline__ float2 sumSlots(const float* __restrict__ base) {
    float a = 0.0f, b = 0.0f;
#pragma unroll
    for (int k = 0; k < 32; ++k) { a += base[2*k]; b += base[2*k+1]; }
    return make_float2(a, b);
}

__device__ __forceinline__ void writeHalf4(__half* __restrict__ rh, int i4, float4 v) {
    union { float2 f2; __half2 h[2]; } u;
    u.h[0] = __floats2half2_rn(v.x, v.y);
    u.h[1] = __floats2half2_rn(v.z, v.w);
    *(float2*)(rh + (i4 << 2)) = u.f2;
}

__global__ void k_zero(float* __restrict__ s, int* __restrict__ cnt) {
    int i = blockIdx.x * blockDim.x + threadIdx.x;
    if (i < 4096) s[i] = 0.0f;
    if (i < M_NODES) cnt[i] = 0;
}

__global__ void k_hist(const int* __restrict__ src, const int* __restrict__ dst,
                       int* __restrict__ cnt) {
    int e = blockIdx.x * blockDim.x + threadIdx.x;
    if (e < E_EDGES) {
        atomicAdd(&cnt[src[e]], 1);
        atomicAdd(&cnt[dst[e]], 1);
    }
}

// ---- multi-block exclusive scan ----
#define SCT 256
#define SCB ((M_NODES + SCT - 1) / SCT)

__global__ __launch_bounds__(SCT) void k_scanA(const int* __restrict__ cnt,
                                               int* __restrict__ partial,
                                               int* __restrict__ btot) {
    __shared__ int sh[SCT];
    int i = blockIdx.x * SCT + threadIdx.x;
    int v = (i < M_NODES) ? cnt[i] : 0;
    sh[threadIdx.x] = v;
    __syncthreads();
    for (int st = 1; st < SCT; st <<= 1) {
        int t = (threadIdx.x >= st) ? sh[threadIdx.x - st] : 0;
        __syncthreads();
        sh[threadIdx.x] += t;
        __syncthreads();
    }
    if (i < M_NODES) partial[i] = sh[threadIdx.x] - v;
    if (threadIdx.x == SCT - 1) btot[blockIdx.x] = sh[SCT - 1];
}

__global__ __launch_bounds__(SCT) void k_scanB(const int* __restrict__ btot,
                                               int* __restrict__ boff,
                                               int* __restrict__ off) {
    __shared__ int sh[SCT];
    int v = (threadIdx.x < SCB) ? btot[threadIdx.x] : 0;
    sh[threadIdx.x] = v;
    __syncthreads();
    for (int st = 1; st < SCT; st <<= 1) {
        int t = (threadIdx.x >= st) ? sh[threadIdx.x - st] : 0;
        __syncthreads();
        sh[threadIdx.x] += t;
        __syncthreads();
    }
    if (threadIdx.x < SCB) boff[threadIdx.x] = sh[threadIdx.x] - v;
    if (threadIdx.x == SCT - 1) off[M_NODES] = sh[SCT - 1];
}

__global__ __launch_bounds__(SCT) void k_scanC(const int* __restrict__ partial,
                                               const int* __restrict__ boff,
                                               int* __restrict__ off,
                                               int* __restrict__ cursor) {
    int i = blockIdx.x * SCT + threadIdx.x;
    if (i < M_NODES) {
        int o = boff[blockIdx.x] + partial[i];
        off[i] = o; cursor[i] = o;
    }
}

__global__ void k_scatter(const int* __restrict__ src, const int* __restrict__ dst,
                          int* __restrict__ cursor, int* __restrict__ pos0,
                          int* __restrict__ pos1, int* __restrict__ nb,
                          int* __restrict__ wk) {
    int e = blockIdx.x * blockDim.x + threadIdx.x;
    if (e < E_EDGES) {
        int s = src[e], t = dst[e];
        int p0 = atomicAdd(&cursor[s], 1);
        pos0[e] = p0; nb[p0] = t; wk[p0] = e;
        int p1 = atomicAdd(&cursor[t], 1);
        pos1[e] = p1; nb[p1] = s; wk[p1] = e + E_EDGES;
    }
}

// 8 lanes/edge, coalesced sequential R reads; scatter-write 128B blocks to CSR slots.
__global__ __launch_bounds__(256) void k_buildC(const float* __restrict__ Rs,
                                                const float* __restrict__ Rd,
                                                const int* __restrict__ pos0,
                                                const int* __restrict__ pos1,
                                                __half* __restrict__ Wc,
                                                __half* __restrict__ GHc, int haveGH) {
    int gt = blockIdx.x * blockDim.x + threadIdx.x;
    int e = gt >> 3, a = gt & 7;
    if (e >= E_EDGES) return;
    const float* rs = Rs + ((size_t)e << 6);
    const float* rd = Rd + ((size_t)e << 6);
    float C[8], Ct[8], G[8], H[8];
#pragma unroll
    for (int j = 0; j < 8; ++j) { C[j] = 0; Ct[j] = 0; G[j] = 0; H[j] = 0; }
#pragma unroll
    for (int c = 0; c < 8; ++c) {
        float xs = rs[c * 8 + a];
        float xd = rd[c * 8 + a];
        float4 s0 = *(const float4*)(rs + c * 8);
        float4 s1 = *(const float4*)(rs + c * 8 + 4);
        float4 d0 = *(const float4*)(rd + c * 8);
        float4 d1 = *(const float4*)(rd + c * 8 + 4);
        C[0] += xs * d0.x; C[1] += xs * d0.y; C[2] += xs * d0.z; C[3] += xs * d0.w;
        C[4] += xs * d1.x; C[5] += xs * d1.y; C[6] += xs * d1.z; C[7] += xs * d1.w;
        Ct[0] += xd * s0.x; Ct[1] += xd * s0.y; Ct[2] += xd * s0.z; Ct[3] += xd * s0.w;
        Ct[4] += xd * s1.x; Ct[5] += xd * s1.y; Ct[6] += xd * s1.z; Ct[7] += xd * s1.w;
        G[0] += xs * s0.x; G[1] += xs * s0.y; G[2] += xs * s0.z; G[3] += xs * s0.w;
        G[4] += xs * s1.x; G[5] += xs * s1.y; G[6] += xs * s1.z; G[7] += xs * s1.w;
        H[0] += xd * d0.x; H[1] += xd * d0.y; H[2] += xd * d0.z; H[3] += xd * d0.w;
        H[4] += xd * d1.x; H[5] += xd * d1.y; H[6] += xd * d1.z; H[7] += xd * d1.w;
    }
    size_t s0o = (size_t)pos0[e] << 6;
    size_t s1o = (size_t)pos1[e] << 6;
    union { float4 f; __half2 h[4]; } u;
#pragma unroll
    for (int k = 0; k < 4; ++k) u.h[k] = __floats2half2_rn(C[2*k], C[2*k+1]);
    *(float4*)(Wc + s0o + (a << 3)) = u.f;
#pragma unroll
    for (int k = 0; k < 4; ++k) u.h[k] = __floats2half2_rn(Ct[2*k], Ct[2*k+1]);
    *(float4*)(Wc + s1o + (a << 3)) = u.f;
    if (haveGH) {
#pragma unroll
        for (int k = 0; k < 4; ++k) u.h[k] = __floats2half2_rn(G[2*k], G[2*k+1]);
        *(float4*)(GHc + s0o + (a << 3)) = u.f;
#pragma unroll
        for (int k = 0; k < 4; ++k) u.h[k] = __floats2half2_rn(H[2*k], H[2*k+1]);
        *(float4*)(GHc + s1o + (a << 3)) = u.f;
    }
}

// diag (fp16) from CSR-streamed GH: wave per node.
__global__ __launch_bounds__(256) void k_diagS(const int* __restrict__ off,
                                               const __half* __restrict__ GHc,
                                               __half* __restrict__ diag) {
    int wave = (blockIdx.x * blockDim.x + threadIdx.x) >> 6;
    int lane = threadIdx.x & 63;
    int g = lane >> 3, a = lane & 7;
    int m = wave;
    if (m >= M_NODES) return;
    float D[8];
#pragma unroll
    for (int j = 0; j < 8; ++j) D[j] = 0.0f;
    int beg = off[m], end = off[m + 1];
    for (int i = beg + g; i < end; i += 8) {
        union { float4 f; __half2 h[4]; } u;
        u.f = *(const float4*)(GHc + ((size_t)i << 6) + (a << 3));
        float2 w0 = __half22float2(u.h[0]);
        float2 w1 = __half22float2(u.h[1]);
        float2 w2 = __half22float2(u.h[2]);
        float2 w3 = __half22float2(u.h[3]);
        D[0] += w0.x; D[1] += w0.y; D[2] += w1.x; D[3] += w1.y;
        D[4] += w2.x; D[5] += w2.y; D[6] += w3.x; D[7] += w3.y;
    }
#pragma unroll
    for (int j = 0; j < 8; ++j) {
        D[j] += __shfl_xor(D[j], 8, 64);
        D[j] += __shfl_xor(D[j], 16, 64);
        D[j] += __shfl_xor(D[j], 32, 64);
    }
    if (g == 0) {
        D[a] += 1.0f;
        union { float4 f; __half2 h[4]; } u;
#pragma unroll
        for (int k = 0; k < 4; ++k) u.h[k] = __floats2half2_rn(D[2*k], D[2*k+1]);
        *(float4*)(diag + ((size_t)m << 6) + (a << 3)) = u.f;
    }
}

// fallback diag straight from R (runs once)
__global__ void k_diagR(const int* __restrict__ off, const int* __restrict__ wk,
                        const float* __restrict__ Rs, const float* __restrict__ Rd,
                        __half* __restrict__ diag) {
    int gt = blockIdx.x * blockDim.x + threadIdx.x;
    int m = gt >> 3, a = gt & 7;
    if (m >= M_NODES) return;
    float D[8];
#pragma unroll
    for (int j = 0; j < 8; ++j) D[j] = 0.0f;
    int beg = off[m], end = off[m + 1];
    for (int i = beg; i < end; ++i) {
        int k = wk[i];
        int side = (k >= E_EDGES);
        int e = k - (side ? E_EDGES : 0);
        const float* R = (side ? Rd : Rs) + ((size_t)e << 6);
#pragma unroll
        for (int c = 0; c < 8; ++c) {
            float xa = R[c * 8 + a];
            float4 y0 = *(const float4*)(R + c * 8);
            float4 y1 = *(const float4*)(R + c * 8 + 4);
            D[0] += xa * y0.x; D[1] += xa * y0.y; D[2] += xa * y0.z; D[3] += xa * y0.w;
            D[4] += xa * y1.x; D[5] += xa * y1.y; D[6] += xa * y1.z; D[7] += xa * y1.w;
        }
    }
    D[a] += 1.0f;
    union { float4 f; __half2 h[4]; } u;
#pragma unroll
    for (int k = 0; k < 4; ++k) u.h[k] = __floats2half2_rn(D[2*k], D[2*k+1]);
    *(float4*)(diag + ((size_t)m << 6) + (a << 3)) = u.f;
}

// one-time: Dinv[m] = inverse of 8x8 diag block (Gauss-Jordan, SPD, no pivoting)
__global__ __launch_bounds__(64) void k_dinv(const __half* __restrict__ diag,
                                             __half* __restrict__ dinv) {
    int m = blockIdx.x * blockDim.x + threadIdx.x;
    if (m >= M_NODES) return;
    float A[8][8], B[8][8];
#pragma unroll
    for (int a = 0; a < 8; ++a) {
        union { float4 f; __half2 h[4]; } u;
        u.f = *(const float4*)(diag + ((size_t)m << 6) + (a << 3));
#pragma unroll
        for (int k = 0; k < 4; ++k) {
            float2 t = __half22float2(u.h[k]);
            A[a][2*k] = t.x; A[a][2*k+1] = t.y;
        }
#pragma unroll
        for (int j = 0; j < 8; ++j) B[a][j] = (a == j) ? 1.0f : 0.0f;
    }
#pragma unroll
    for (int k = 0; k < 8; ++k) {
        float piv = 1.0f / A[k][k];
#pragma unroll
        for (int j = 0; j < 8; ++j) { A[k][j] *= piv; B[k][j] *= piv; }
#pragma unroll
        for (int i = 0; i < 8; ++i) {
            if (i != k) {
                float f = A[i][k];
#pragma unroll
                for (int j = 0; j < 8; ++j) { A[i][j] -= f * A[k][j]; B[i][j] -= f * B[k][j]; }
            }
        }
    }
#pragma unroll
    for (int a = 0; a < 8; ++a) {
        union { float4 f; __half2 h[4]; } u;
#pragma unroll
        for (int k = 0; k < 4; ++k) u.h[k] = __floats2half2_rn(B[a][2*k], B[a][2*k+1]);
        *(float4*)(dinv + ((size_t)m << 6) + (a << 3)) = u.f;
    }
}

// layout convert: orig [b][m][8] -> fp16 interleaved mirror [m][16]
__global__ void k_cvt(const float4* __restrict__ src, __half* __restrict__ ilh) {
    int i = blockIdx.x * blockDim.x + threadIdx.x;
    if (i >= N4) return;
    int b = i / (PER_B / 4);
    int rem = i - b * (PER_B / 4);
    int m = rem >> 1, half = rem & 1;
    int d = (m << 2) + (b << 1) + half;
    writeHalf4(ilh, d, src[i]);
}

// w = A z  (fp16 gather mirror zh). Wave/node grid-strided; unrolled x2.
// Fused dot: mu = z.w -> slots.
__global__ __launch_bounds__(256) void k_mv(const __half* __restrict__ rh,
                                            float* __restrict__ wv,
                                            const int* __restrict__ off,
                                            const int* __restrict__ nbA,
                                            const __half* __restrict__ Wc,
                                            const __half* __restrict__ diag,
                                            float* __restrict__ mu) {
    int lane = threadIdx.x & 63;
    int g = lane >> 3, a = lane & 7;
    int waveId = (blockIdx.x * blockDim.x + threadIdx.x) >> 6;
    int nWaves = (gridDim.x * blockDim.x) >> 6;
    float mu0 = 0.f, mu1 = 0.f;
    for (int m = waveId; m < M_NODES; m += nWaves) {
        int beg = off[m], end = off[m + 1];
        float acc0 = 0.f, acc1 = 0.f;
        int i = beg + g;
        for (; i + 8 < end; i += 16) {
            int nA = nbA[i];
            int nB = nbA[i + 8];
            union { float4 f; __half2 h[4]; } uA, uB, rA0, rA1, rB0, rB1;
            uA.f = *(const float4*)(Wc + ((size_t)i << 6) + (a << 3));
            uB.f = *(const float4*)(Wc + ((size_t)(i + 8) << 6) + (a << 3));
            rA0.f = *(const float4*)(rh + (nA << 4));
            rA1.f = *(const float4*)(rh + (nA << 4) + 8);
            rB0.f = *(const float4*)(rh + (nB << 4));
            rB1.f = *(const float4*)(rh + (nB << 4) + 8);
            float2 wA0 = __half22float2(uA.h[0]);
            float2 wA1 = __half22float2(uA.h[1]);
            float2 wA2 = __half22float2(uA.h[2]);
            float2 wA3 = __half22float2(uA.h[3]);
            float2 a00 = __half22float2(rA0.h[0]);
            float2 a01 = __half22float2(rA0.h[1]);
            float2 a02 = __half22float2(rA0.h[2]);
            float2 a03 = __half22float2(rA0.h[3]);
            float2 a10 = __half22float2(rA1.h[0]);
            float2 a11 = __half22float2(rA1.h[1]);
            float2 a12 = __half22float2(rA1.h[2]);
            float2 a13 = __half22float2(rA1.h[3]);
            acc0 += wA0.x*a00.x + wA0.y*a00.y + wA1.x*a01.x + wA1.y*a01.y
                  + wA2.x*a02.x + wA2.y*a02.y + wA3.x*a03.x + wA3.y*a03.y;
            acc1 += wA0.x*a10.x + wA0.y*a10.y + wA1.x*a11.x + wA1.y*a11.y
                  + wA2.x*a12.x + wA2.y*a12.y + wA3.x*a13.x + wA3.y*a13.y;
            float2 wB0 = __half22float2(uB.h[0]);
            float2 wB1 = __half22float2(uB.h[1]);
            float2 wB2 = __half22float2(uB.h[2]);
            float2 wB3 = __half22float2(uB.h[3]);
            float2 b00 = __half22float2(rB0.h[0]);
            float2 b01 = __half22float2(rB0.h[1]);
            float2 b02 = __half22float2(rB0.h[2]);
            float2 b03 = __half22float2(rB0.h[3]);
            float2 b10 = __half22float2(rB1.h[0]);
            float2 b11 = __half22float2(rB1.h[1]);
            float2 b12 = __half22float2(rB1.h[2]);
            float2 b13 = __half22float2(rB1.h[3]);
            acc0 += wB0.x*b00.x + wB0.y*b00.y + wB1.x*b01.x + wB1.y*b01.y
                  + wB2.x*b02.x + wB2.y*b02.y + wB3.x*b03.x + wB3.y*b03.y;
            acc1 += wB0.x*b10.x + wB0.y*b10.y + wB1.x*b11.x + wB1.y*b11.y
                  + wB2.x*b12.x + wB2.y*b12.y + wB3.x*b13.x + wB3.y*b13.y;
        }
        if (i < end) {
            int n = nbA[i];
            union { float4 f; __half2 h[4]; } u, r0, r1;
            u.f = *(const float4*)(Wc + ((size_t)i << 6) + (a << 3));
            r0.f = *(const float4*)(rh + (n << 4));
            r1.f = *(const float4*)(rh + (n << 4) + 8);
            float2 w0 = __half22float2(u.h[0]);
            float2 w1 = __half22float2(u.h[1]);
            float2 w2 = __half22float2(u.h[2]);
            float2 w3 = __half22float2(u.h[3]);
            float2 c00 = __half22float2(r0.h[0]);
            float2 c01 = __half22float2(r0.h[1]);
            float2 c02 = __half22float2(r0.h[2]);
            float2 c03 = __half22float2(r0.h[3]);
            float2 c10 = __half22float2(r1.h[0]);
            float2 c11 = __half22float2(r1.h[1]);
            float2 c12 = __half22float2(r1.h[2]);
            float2 c13 = __half22float2(r1.h[3]);
            acc0 += w0.x*c00.x + w0.y*c00.y + w1.x*c01.x + w1.y*c01.y
                  + w2.x*c02.x + w2.y*c02.y + w3.x*c03.x + w3.y*c03.y;
            acc1 += w0.x*c10.x + w0.y*c10.y + w1.x*c11.x + w1.y*c11.y
                  + w2.x*c12.x + w2.y*c12.y + w3.x*c13.x + w3.y*c13.y;
        }
        acc0 += __shfl_xor(acc0, 8, 64);  acc1 += __shfl_xor(acc1, 8, 64);
        acc0 += __shfl_xor(acc0, 16, 64); acc1 += __shfl_xor(acc1, 16, 64);
        acc0 += __shfl_xor(acc0, 32, 64); acc1 += __shfl_xor(acc1, 32, 64);
        if (g < 2) {
            union { float4 f; __half2 h[4]; } ur, ud;
            ur.f = *(const float4*)(rh + (m << 4) + (g << 3));
            ud.f = *(const float4*)(diag + ((size_t)m << 6) + (a << 3));
            float rm[8];
            float2 t;
            t = __half22float2(ur.h[0]); rm[0] = t.x; rm[1] = t.y;
            t = __half22float2(ur.h[1]); rm[2] = t.x; rm[3] = t.y;
            t = __half22float2(ur.h[2]); rm[4] = t.x; rm[5] = t.y;
            t = __half22float2(ur.h[3]); rm[6] = t.x; rm[7] = t.y;
            float2 g0 = __half22float2(ud.h[0]);
            float2 g1 = __half22float2(ud.h[1]);
            float2 g2 = __half22float2(ud.h[2]);
            float2 g3 = __half22float2(ud.h[3]);
            float acc = g ? acc1 : acc0;
            float w = g0.x*rm[0] + g0.y*rm[1] + g1.x*rm[2] + g1.y*rm[3]
                    + g2.x*rm[4] + g2.y*rm[5] + g3.x*rm[6] + g3.y*rm[7] - acc;
            wv[(m << 4) + (g << 3) + a] = w;
            float ra = rm[a];
            if (g == 0) mu0 += ra * w; else mu1 += ra * w;
        }
    }
    blockReduceAdd2(mu0, mu1, mu);
}

// init: thread per (m,b). r = b - w; x = b; z = Dinv r; zh; rho0 = r.z
__global__ __launch_bounds__(256) void k_init0(const float4* __restrict__ c0,
                                               const float4* __restrict__ w,
                                               float4* __restrict__ r,
                                               float4* __restrict__ x,
                                               float4* __restrict__ z,
                                               __half* __restrict__ zh,
                                               const __half* __restrict__ dinv,
                                               float* __restrict__ rho0) {
    int u = blockIdx.x * blockDim.x + threadIdx.x;
    float s0 = 0.f, s1 = 0.f;
    if (u < M_NODES * 2) {
        int m = u >> 1, bb = u & 1;
        int f4 = (m << 2) + (bb << 1);
        float4 b0 = c0[bb * (PER_B / 4) + (m << 1)];
        float4 b1 = c0[bb * (PER_B / 4) + (m << 1) + 1];
        float4 w0 = w[f4], w1 = w[f4 + 1];
        float rr[8];
        rr[0] = b0.x - w0.x; rr[1] = b0.y - w0.y; rr[2] = b0.z - w0.z; rr[3] = b0.w - w0.w;
        rr[4] = b1.x - w1.x; rr[5] = b1.y - w1.y; rr[6] = b1.z - w1.z; rr[7] = b1.w - w1.w;
        x[f4] = b0; x[f4 + 1] = b1;
        r[f4] = make_float4(rr[0], rr[1], rr[2], rr[3]);
        r[f4 + 1] = make_float4(rr[4], rr[5], rr[6], rr[7]);
        float zz[8];
        const __half* dv = dinv + ((size_t)m << 6);
#pragma unroll
        for (int a = 0; a < 8; ++a) {
            union { float4 f; __half2 h[4]; } u2;
            u2.f = *(const float4*)(dv + (a << 3));
            float2 t0 = __half22float2(u2.h[0]);
            float2 t1 = __half22float2(u2.h[1]);
            float2 t2 = __half22float2(u2.h[2]);
            float2 t3 = __half22float2(u2.h[3]);
            zz[a] = t0.x*rr[0] + t0.y*rr[1] + t1.x*rr[2] + t1.y*rr[3]
                  + t2.x*rr[4] + t2.y*rr[5] + t3.x*rr[6] + t3.y*rr[7];
        }
        float4 z0 = make_float4(zz[0], zz[1], zz[2], zz[3]);
        float4 z1 = make_float4(zz[4], zz[5], zz[6], zz[7]);
        z[f4] = z0; z[f4 + 1] = z1;
        writeHalf4(zh, f4, z0);
        writeHalf4(zh, f4 + 1, z1);
        float d = rr[0]*zz[0] + rr[1]*zz[1] + rr[2]*zz[2] + rr[3]*zz[3]
                + rr[4]*zz[4] + rr[5]*zz[5] + rr[6]*zz[6] + rr[7]*zz[7];
        if (bb == 0) s0 = d; else s1 = d;
    }
    blockReduceAdd2(s0, s1, rho0);
}

// C-G PCG update: thread per (m,b), grid-stride. Scalars once/block.
// p = z + beta p; q = w + beta q; x += alpha p; r -= alpha q;
// z = Dinv r (+zh); rho_next = r.z. Last iter: only out = x.
__global__ __launch_bounds__(256) void k_axpy(float4* __restrict__ x,
                                              float4* __restrict__ r,
                                              float4* __restrict__ z,
                                              __half* __restrict__ zh,
                                              float4* __restrict__ p,
                                              float4* __restrict__ q,
                                              const float4* __restrict__ w,
                                              const __half* __restrict__ dinv,
                                              const float* __restrict__ rho_s,
                                              const float* __restrict__ mu_s,
                                              float* __restrict__ fin,
                                              float* __restrict__ rho_next,
                                              int j, int last,
                                              float4* __restrict__ out) {
    __shared__ float sc[4];
    if (threadIdx.x == 0) {
        float2 rho = sumSlots(rho_s);
        float2 mu  = sumSlots(mu_s);
        float b0, b1, al0, al1;
        if (j == 0) {
            b0 = b1 = 0.0f;
            al0 = rho.x / (mu.x + EPSF);
            al1 = rho.y / (mu.y + EPSF);
        } else {
            float ap0 = fin[4*(j-1)+0], ap1 = fin[4*(j-1)+1];
            float rp0 = fin[4*(j-1)+2], rp1 = fin[4*(j-1)+3];
            b0 = rho.x / (rp0 + EPSF);
            b1 = rho.y / (rp1 + EPSF);
            al0 = rho.x / (mu.x - b0 * rho.x / (ap0 + EPSF) + EPSF);
            al1 = rho.y / (mu.y - b1 * rho.y / (ap1 + EPSF) + EPSF);
        }
        if (!last && blockIdx.x == 0) {
            fin[4*j] = al0; fin[4*j+1] = al1; fin[4*j+2] = rho.x; fin[4*j+3] = rho.y;
        }
        sc[0] = al0; sc[1] = al1; sc[2] = b0; sc[3] = b1;
    }
    __syncthreads();
    float al0 = sc[0], al1 = sc[1], b0s = sc[2], b1s = sc[3];
    float s0 = 0.f, s1 = 0.f;
    for (int u = blockIdx.x * blockDim.x + threadIdx.x; u < M_NODES * 2;
         u += gridDim.x * blockDim.x) {
        int m = u >> 1, bb = u & 1;
        int f4 = (m << 2) + (bb << 1);
        float be = bb ? b1s : b0s;
        float al = bb ? al1 : al0;
        float4 zv0 = z[f4], zv1 = z[f4 + 1];
        float4 wv0 = w[f4], wv1 = w[f4 + 1];
        float4 pn0, pn1, qn0, qn1;
        if (j == 0) { pn0 = zv0; pn1 = zv1; qn0 = wv0; qn1 = wv1; }
        else {
            float4 pv0 = p[f4], pv1 = p[f4 + 1];
            float4 qv0 = q[f4], qv1 = q[f4 + 1];
            pn0 = make_float4(zv0.x + be*pv0.x, zv0.y + be*pv0.y, zv0.z + be*pv0.z, zv0.w + be*pv0.w);
            pn1 = make_float4(zv1.x + be*pv1.x, zv1.y + be*pv1.y, zv1.z + be*pv1.z, zv1.w + be*pv1.w);
            qn0 = make_float4(wv0.x + be*qv0.x, wv0.y + be*qv0.y, wv0.z + be*qv0.z, wv0.w + be*qv0.w);
            qn1 = make_float4(wv1.x + be*qv1.x, wv1.y + be*qv1.y, wv1.z + be*qv1.z, wv1.w + be*qv1.w);
        }
        float4 xv0 = x[f4], xv1 = x[f4 + 1];
        float4 xn0 = make_float4(xv0.x + al*pn0.x, xv0.y + al*pn0.y, xv0.z + al*pn0.z, xv0.w + al*pn0.w);
        float4 xn1 = make_float4(xv1.x + al*pn1.x, xv1.y + al*pn1.y, xv1.z + al*pn1.z, xv1.w + al*pn1.w);
        if (last) {
            out[bb * (PER_B / 4) + (m << 1)] = xn0;
            out[bb * (PER_B / 4) + (m << 1) + 1] = xn1;
        } else {
            float4 rv0 = r[f4], rv1 = r[f4 + 1];
            float rr[8];
            rr[0] = rv0.x - al*qn0.x; rr[1] = rv0.y - al*qn0.y;
            rr[2] = rv0.z - al*qn0.z; rr[3] = rv0.w - al*qn0.w;
            rr[4] = rv1.x - al*qn1.x; rr[5] = rv1.y - al*qn1.y;
            rr[6] = rv1.z - al*qn1.z; rr[7] = rv1.w - al*qn1.w;
            x[f4] = xn0; x[f4 + 1] = xn1;
            r[f4] = make_float4(rr[0], rr[1], rr[2], rr[3]);
            r[f4 + 1] = make_float4(rr[4], rr[5], rr[6], rr[7]);
            p[f4] = pn0; p[f4 + 1] = pn1;
            q[f4] = qn0; q[f4 + 1] = qn1;
            float zz[8];
            const __half* dv = dinv + ((size_t)m << 6);
#pragma unroll
            for (int a = 0; a < 8; ++a) {
                union { float4 f; __half2 h[4]; } u2;
                u2.f = *(const float4*)(dv + (a << 3));
                float2 t0 = __half22float2(u2.h[0]);
                float2 t1 = __half22float2(u2.h[1]);
                float2 t2 = __half22float2(u2.h[2]);
                float2 t3 = __half22float2(u2.h[3]);
                zz[a] = t0.x*rr[0] + t0.y*rr[1] + t1.x*rr[2] + t1.y*rr[3]
                      + t2.x*rr[4] + t2.y*rr[5] + t3.x*rr[6] + t3.y*rr[7];
            }
            float4 z0 = make_float4(zz[0], zz[1], zz[2], zz[3]);
            float4 z1 = make_float4(zz[4], zz[5], zz[6], zz[7]);
            z[f4] = z0; z[f4 + 1] = z1;
            writeHalf4(zh, f4, z0);
            writeHalf4(zh, f4 + 1, z1);
            float d = rr[0]*zz[0] + rr[1]*zz[1] + rr[2]*zz[2] + rr[3]*zz[3]
                    + rr[4]*zz[4] + rr[5]*zz[5] + rr[6]*zz[6] + rr[7]*zz[7];
            if (bb == 0) s0 += d; else s1 += d;
        }
    }
    if (!last) blockReduceAdd2(s0, s1, rho_next);
}

extern "C" void kernel_launch(void* const* d_in, const int* in_sizes, int n_in,
                              void* d_out, int out_size, void* d_ws, size_t ws_size,
                              hipStream_t stream) {
    const float* c0 = (const float*)d_in[0];
    const int* src  = (const int*)d_in[1];
    const int* dst  = (const int*)d_in[2];
    const float* Rs = (const float*)d_in[3];
    const float* Rd = (const float*)d_in[4];

    char* wsp = (char*)d_ws;
    size_t o = 0;
    auto alloc = [&](size_t bytes) { char* c = wsp + o; o = (o + bytes + 255) & ~(size_t)255; return c; };
    float* r      = (float*)alloc(VEC_N * 4);
    float* wv     = (float*)alloc(VEC_N * 4);
    float* p      = (float*)alloc(VEC_N * 4);
    float* q      = (float*)alloc(VEC_N * 4);
    float* x      = (float*)alloc(VEC_N * 4);
    float* z      = (float*)alloc(VEC_N * 4);
    __half* zh    = (__half*)alloc(VEC_N * 2);
    __half* bh    = (__half*)alloc(VEC_N * 2);
    float* scal   = (float*)alloc(4096 * 4);
    int*   cnt    = (int*)alloc(M_NODES * 4);
    int*   offa   = (int*)alloc((M_NODES + 1) * 4);
    int*   cursor = (int*)alloc(M_NODES * 4);
    int*   partial= (int*)alloc(M_NODES * 4);
    int*   btot   = (int*)alloc(SCB * 4);
    int*   boff   = (int*)alloc(SCB * 4);
    int*   pos0   = (int*)alloc(E_EDGES * 4);
    int*   pos1   = (int*)alloc(E_EDGES * 4);
    int*   wk     = (int*)alloc(N_INC * 4);
    int*   nb     = (int*)alloc(N_INC * 4);
    __half* diag  = (__half*)alloc((size_t)M_NODES * 64 * 2);
    __half* dinv  = (__half*)alloc((size_t)M_NODES * 64 * 2);
    __half* Wc    = (__half*)alloc((size_t)N_INC * 64 * 2);
    size_t ghBytes = (size_t)N_INC * 64 * 2;
    int haveGH = (o + ghBytes) <= ws_size;
    __half* GHc = haveGH ? (__half*)alloc(ghBytes) : (__half*)Wc;

    const int BLK = 256;
    const int grid_v  = (N4 + BLK - 1) / BLK;
    const int grid_e  = (E_EDGES + BLK - 1) / BLK;
    const int grid_m  = (M_NODES + BLK - 1) / BLK;
    const int grid_e8 = (E_EDGES * 8 + BLK - 1) / BLK;
    const int grid_m8 = (M_NODES * 8 + BLK - 1) / BLK;
    const int grid_mw = (M_NODES * 64 + BLK - 1) / BLK;
    const int grid_u  = (M_NODES * 2 + BLK - 1) / BLK;
    const int MVB     = 2048;
    const int AXB     = 392;

    float* RHO = scal;             // RHO(t) = scal + 64*t
    float* MU  = scal + 1024;      // MU(t)  = scal + 1024 + 64*t
    float* FIN = scal + 3968;

    // ---- precompute (rebuilt every call) ----
    k_zero<<<grid_m, BLK, 0, stream>>>(scal, cnt);
    k_hist<<<grid_e, BLK, 0, stream>>>(src, dst, cnt);
    k_scanA<<<SCB, SCT, 0, stream>>>(cnt, partial, btot);
    k_scanB<<<1, SCT, 0, stream>>>(btot, boff, offa);
    k_scanC<<<SCB, SCT, 0, stream>>>(partial, boff, offa, cursor);
    k_scatter<<<grid_e, BLK, 0, stream>>>(src, dst, cursor, pos0, pos1, nb, wk);
    k_buildC<<<grid_e8, BLK, 0, stream>>>(Rs, Rd, pos0, pos1, Wc, GHc, haveGH);
    if (haveGH)
        k_diagS<<<grid_mw, BLK, 0, stream>>>(offa, GHc, diag);
    else
        k_diagR<<<grid_m8, BLK, 0, stream>>>(offa, wk, Rs, Rd, diag);
    k_dinv<<<(M_NODES + 63) / 64, 64, 0, stream>>>(diag, dinv);

    // ---- init: bh = fp16(interleave(c0)); w = A b; r,x,z,zh,rho0 ----
    k_cvt<<<grid_v, BLK, 0, stream>>>((const float4*)c0, bh);
    k_mv<<<MVB, BLK, 0, stream>>>(bh, wv, offa, nb, Wc, diag, MU + 64 * 12);
    k_init0<<<grid_u, BLK, 0, stream>>>((const float4*)c0, (const float4*)wv,
                                        (float4*)r, (float4*)x, (float4*)z, zh,
                                        dinv, RHO);

    // ---- C-G PCG: 2 kernels/iter, matvec on zh ----
    for (int t = 0; t < CG_ITERS; ++t) {
        k_mv<<<MVB, BLK, 0, stream>>>(zh, wv, offa, nb, Wc, diag, MU + 64 * t);
        k_axpy<<<AXB, BLK, 0, stream>>>((float4*)x, (float4*)r, (float4*)z, zh,
                                        (float4*)p, (float4*)q, (const float4*)wv,
                                        dinv, RHO + 64 * t, MU + 64 * t, FIN,
                                        RHO + 64 * (t + 1), t,
                                        (t == CG_ITERS - 1) ? 1 : 0,
                                        (float4*)d_out);
    }
}

// Round 16
// 599.691 us; speedup vs baseline: 4.1612x; 1.1128x over previous
//
#include <hip/hip_runtime.h>
#include <hip/hip_fp16.h>

#define E_EDGES   400000
#define M_NODES   50000
#define N_INC     800000
#define PER_B     400000
#define VEC_N     800000
#define N4        200000
#define CG_ITERS  5
#define EPSF      1e-12f

// scal (4096 floats): 32 slot-pairs (64 floats) per instance.
//   RHO(t) = scal + 64*t           t=0..12
//   MU(t)  = scal + 1024 + 64*t    t=0..12  (t=12 = init-mv scratch)
//   fin    = scal + 3968 : fin[4t+0/1]=alpha_t(b0/b1), fin[4t+2/3]=rho_t(b0/b1)

__device__ __forceinline__ float waveReduce(float v) {
#pragma unroll
    for (int off = 32; off > 0; off >>= 1)
        v += __shfl_down(v, off, 64);
    return v;
}

__device__ __forceinline__ void blockReduceAdd2(float d0, float d1, float* __restrict__ base) {
    __shared__ float red[8];
    d0 = waveReduce(d0);
    d1 = waveReduce(d1);
    int w = threadIdx.x >> 6, lane = threadIdx.x & 63;
    if (lane == 0) { red[2*w] = d0; red[2*w+1] = d1; }
    __syncthreads();
    if (threadIdx.x == 0) {
        float t0 = red[0] + red[2] + red[4] + red[6];
        float t1 = red[1] + red[3] + red[5] + red[7];
        int s = (blockIdx.x & 31) << 1;
        atomicAdd(&base[s], t0);
        atomicAdd(&base[s + 1], t1);
    }
}

__device__ __forceinline__ float2 sumSlots(const float* __restrict__ base) {
    float a = 0.0f, b = 0.0f;
#pragma unroll
    for (int k = 0; k < 32; ++k) { a += base[2*k]; b += base[2*k+1]; }
    return make_float2(a, b);
}

__device__ __forceinline__ void writeHalf4(__half* __restrict__ rh, int i4, float4 v) {
    union { float2 f2; __half2 h[2]; } u;
    u.h[0] = __floats2half2_rn(v.x, v.y);
    u.h[1] = __floats2half2_rn(v.z, v.w);
    *(float2*)(rh + (i4 << 2)) = u.f2;
}

// prologue: zero scal + cnt, and bh = fp16(interleave(c0)) — one launch
__global__ void k_prolog(float* __restrict__ s, int* __restrict__ cnt,
                         const float4* __restrict__ src, __half* __restrict__ ilh) {
    int i = blockIdx.x * blockDim.x + threadIdx.x;
    if (i < 4096) s[i] = 0.0f;
    if (i < M_NODES) cnt[i] = 0;
    if (i < N4) {
        int b = i / (PER_B / 4);
        int rem = i - b * (PER_B / 4);
        int m = rem >> 1, half = rem & 1;
        int d = (m << 2) + (b << 1) + half;
        writeHalf4(ilh, d, src[i]);
    }
}

__global__ void k_hist(const int* __restrict__ src, const int* __restrict__ dst,
                       int* __restrict__ cnt) {
    int e = blockIdx.x * blockDim.x + threadIdx.x;
    if (e < E_EDGES) {
        atomicAdd(&cnt[src[e]], 1);
        atomicAdd(&cnt[dst[e]], 1);
    }
}

// ---- multi-block exclusive scan ----
#define SCT 256
#define SCB ((M_NODES + SCT - 1) / SCT)

__global__ __launch_bounds__(SCT) void k_scanA(const int* __restrict__ cnt,
                                               int* __restrict__ partial,
                                               int* __restrict__ btot) {
    __shared__ int sh[SCT];
    int i = blockIdx.x * SCT + threadIdx.x;
    int v = (i < M_NODES) ? cnt[i] : 0;
    sh[threadIdx.x] = v;
    __syncthreads();
    for (int st = 1; st < SCT; st <<= 1) {
        int t = (threadIdx.x >= st) ? sh[threadIdx.x - st] : 0;
        __syncthreads();
        sh[threadIdx.x] += t;
        __syncthreads();
    }
    if (i < M_NODES) partial[i] = sh[threadIdx.x] - v;
    if (threadIdx.x == SCT - 1) btot[blockIdx.x] = sh[SCT - 1];
}

__global__ __launch_bounds__(SCT) void k_scanB(const int* __restrict__ btot,
                                               int* __restrict__ boff,
                                               int* __restrict__ off) {
    __shared__ int sh[SCT];
    int v = (threadIdx.x < SCB) ? btot[threadIdx.x] : 0;
    sh[threadIdx.x] = v;
    __syncthreads();
    for (int st = 1; st < SCT; st <<= 1) {
        int t = (threadIdx.x >= st) ? sh[threadIdx.x - st] : 0;
        __syncthreads();
        sh[threadIdx.x] += t;
        __syncthreads();
    }
    if (threadIdx.x < SCB) boff[threadIdx.x] = sh[threadIdx.x] - v;
    if (threadIdx.x == SCT - 1) off[M_NODES] = sh[SCT - 1];
}

__global__ __launch_bounds__(SCT) void k_scanC(const int* __restrict__ partial,
                                               const int* __restrict__ boff,
                                               int* __restrict__ off,
                                               int* __restrict__ cursor) {
    int i = blockIdx.x * SCT + threadIdx.x;
    if (i < M_NODES) {
        int o = boff[blockIdx.x] + partial[i];
        off[i] = o; cursor[i] = o;
    }
}

__global__ void k_scatter(const int* __restrict__ src, const int* __restrict__ dst,
                          int* __restrict__ cursor, int* __restrict__ pos0,
                          int* __restrict__ pos1, int* __restrict__ nb,
                          int* __restrict__ wk) {
    int e = blockIdx.x * blockDim.x + threadIdx.x;
    if (e < E_EDGES) {
        int s = src[e], t = dst[e];
        int p0 = atomicAdd(&cursor[s], 1);
        pos0[e] = p0; nb[p0] = t; wk[p0] = e;
        int p1 = atomicAdd(&cursor[t], 1);
        pos1[e] = p1; nb[p1] = s; wk[p1] = e + E_EDGES;
    }
}

// 8 lanes/edge, coalesced sequential R reads; scatter-write 128B blocks to CSR slots.
__global__ __launch_bounds__(256) void k_buildC(const float* __restrict__ Rs,
                                                const float* __restrict__ Rd,
                                                const int* __restrict__ pos0,
                                                const int* __restrict__ pos1,
                                                __half* __restrict__ Wc,
                                                __half* __restrict__ GHc, int haveGH) {
    int gt = blockIdx.x * blockDim.x + threadIdx.x;
    int e = gt >> 3, a = gt & 7;
    if (e >= E_EDGES) return;
    const float* rs = Rs + ((size_t)e << 6);
    const float* rd = Rd + ((size_t)e << 6);
    float C[8], Ct[8], G[8], H[8];
#pragma unroll
    for (int j = 0; j < 8; ++j) { C[j] = 0; Ct[j] = 0; G[j] = 0; H[j] = 0; }
#pragma unroll
    for (int c = 0; c < 8; ++c) {
        float xs = rs[c * 8 + a];
        float xd = rd[c * 8 + a];
        float4 s0 = *(const float4*)(rs + c * 8);
        float4 s1 = *(const float4*)(rs + c * 8 + 4);
        float4 d0 = *(const float4*)(rd + c * 8);
        float4 d1 = *(const float4*)(rd + c * 8 + 4);
        C[0] += xs * d0.x; C[1] += xs * d0.y; C[2] += xs * d0.z; C[3] += xs * d0.w;
        C[4] += xs * d1.x; C[5] += xs * d1.y; C[6] += xs * d1.z; C[7] += xs * d1.w;
        Ct[0] += xd * s0.x; Ct[1] += xd * s0.y; Ct[2] += xd * s0.z; Ct[3] += xd * s0.w;
        Ct[4] += xd * s1.x; Ct[5] += xd * s1.y; Ct[6] += xd * s1.z; Ct[7] += xd * s1.w;
        G[0] += xs * s0.x; G[1] += xs * s0.y; G[2] += xs * s0.z; G[3] += xs * s0.w;
        G[4] += xs * s1.x; G[5] += xs * s1.y; G[6] += xs * s1.z; G[7] += xs * s1.w;
        H[0] += xd * d0.x; H[1] += xd * d0.y; H[2] += xd * d0.z; H[3] += xd * d0.w;
        H[4] += xd * d1.x; H[5] += xd * d1.y; H[6] += xd * d1.z; H[7] += xd * d1.w;
    }
    size_t s0o = (size_t)pos0[e] << 6;
    size_t s1o = (size_t)pos1[e] << 6;
    union { float4 f; __half2 h[4]; } u;
#pragma unroll
    for (int k = 0; k < 4; ++k) u.h[k] = __floats2half2_rn(C[2*k], C[2*k+1]);
    *(float4*)(Wc + s0o + (a << 3)) = u.f;
#pragma unroll
    for (int k = 0; k < 4; ++k) u.h[k] = __floats2half2_rn(Ct[2*k], Ct[2*k+1]);
    *(float4*)(Wc + s1o + (a << 3)) = u.f;
    if (haveGH) {
#pragma unroll
        for (int k = 0; k < 4; ++k) u.h[k] = __floats2half2_rn(G[2*k], G[2*k+1]);
        *(float4*)(GHc + s0o + (a << 3)) = u.f;
#pragma unroll
        for (int k = 0; k < 4; ++k) u.h[k] = __floats2half2_rn(H[2*k], H[2*k+1]);
        *(float4*)(GHc + s1o + (a << 3)) = u.f;
    }
}

// diag (fp16) from CSR-streamed GH: wave per node.
__global__ __launch_bounds__(256) void k_diagS(const int* __restrict__ off,
                                               const __half* __restrict__ GHc,
                                               __half* __restrict__ diag) {
    int wave = (blockIdx.x * blockDim.x + threadIdx.x) >> 6;
    int lane = threadIdx.x & 63;
    int g = lane >> 3, a = lane & 7;
    int m = wave;
    if (m >= M_NODES) return;
    float D[8];
#pragma unroll
    for (int j = 0; j < 8; ++j) D[j] = 0.0f;
    int beg = off[m], end = off[m + 1];
    for (int i = beg + g; i < end; i += 8) {
        union { float4 f; __half2 h[4]; } u;
        u.f = *(const float4*)(GHc + ((size_t)i << 6) + (a << 3));
        float2 w0 = __half22float2(u.h[0]);
        float2 w1 = __half22float2(u.h[1]);
        float2 w2 = __half22float2(u.h[2]);
        float2 w3 = __half22float2(u.h[3]);
        D[0] += w0.x; D[1] += w0.y; D[2] += w1.x; D[3] += w1.y;
        D[4] += w2.x; D[5] += w2.y; D[6] += w3.x; D[7] += w3.y;
    }
#pragma unroll
    for (int j = 0; j < 8; ++j) {
        D[j] += __shfl_xor(D[j], 8, 64);
        D[j] += __shfl_xor(D[j], 16, 64);
        D[j] += __shfl_xor(D[j], 32, 64);
    }
    if (g == 0) {
        D[a] += 1.0f;
        union { float4 f; __half2 h[4]; } u;
#pragma unroll
        for (int k = 0; k < 4; ++k) u.h[k] = __floats2half2_rn(D[2*k], D[2*k+1]);
        *(float4*)(diag + ((size_t)m << 6) + (a << 3)) = u.f;
    }
}

// fallback diag straight from R (runs once)
__global__ void k_diagR(const int* __restrict__ off, const int* __restrict__ wk,
                        const float* __restrict__ Rs, const float* __restrict__ Rd,
                        __half* __restrict__ diag) {
    int gt = blockIdx.x * blockDim.x + threadIdx.x;
    int m = gt >> 3, a = gt & 7;
    if (m >= M_NODES) return;
    float D[8];
#pragma unroll
    for (int j = 0; j < 8; ++j) D[j] = 0.0f;
    int beg = off[m], end = off[m + 1];
    for (int i = beg; i < end; ++i) {
        int k = wk[i];
        int side = (k >= E_EDGES);
        int e = k - (side ? E_EDGES : 0);
        const float* R = (side ? Rd : Rs) + ((size_t)e << 6);
#pragma unroll
        for (int c = 0; c < 8; ++c) {
            float xa = R[c * 8 + a];
            float4 y0 = *(const float4*)(R + c * 8);
            float4 y1 = *(const float4*)(R + c * 8 + 4);
            D[0] += xa * y0.x; D[1] += xa * y0.y; D[2] += xa * y0.z; D[3] += xa * y0.w;
            D[4] += xa * y1.x; D[5] += xa * y1.y; D[6] += xa * y1.z; D[7] += xa * y1.w;
        }
    }
    D[a] += 1.0f;
    union { float4 f; __half2 h[4]; } u;
#pragma unroll
    for (int k = 0; k < 4; ++k) u.h[k] = __floats2half2_rn(D[2*k], D[2*k+1]);
    *(float4*)(diag + ((size_t)m << 6) + (a << 3)) = u.f;
}

// one-time: Dinv[m] = inverse of 8x8 diag block (Gauss-Jordan, SPD, no pivoting)
__global__ __launch_bounds__(64) void k_dinv(const __half* __restrict__ diag,
                                             __half* __restrict__ dinv) {
    int m = blockIdx.x * blockDim.x + threadIdx.x;
    if (m >= M_NODES) return;
    float A[8][8], B[8][8];
#pragma unroll
    for (int a = 0; a < 8; ++a) {
        union { float4 f; __half2 h[4]; } u;
        u.f = *(const float4*)(diag + ((size_t)m << 6) + (a << 3));
#pragma unroll
        for (int k = 0; k < 4; ++k) {
            float2 t = __half22float2(u.h[k]);
            A[a][2*k] = t.x; A[a][2*k+1] = t.y;
        }
#pragma unroll
        for (int j = 0; j < 8; ++j) B[a][j] = (a == j) ? 1.0f : 0.0f;
    }
#pragma unroll
    for (int k = 0; k < 8; ++k) {
        float piv = 1.0f / A[k][k];
#pragma unroll
        for (int j = 0; j < 8; ++j) { A[k][j] *= piv; B[k][j] *= piv; }
#pragma unroll
        for (int i = 0; i < 8; ++i) {
            if (i != k) {
                float f = A[i][k];
#pragma unroll
                for (int j = 0; j < 8; ++j) { A[i][j] -= f * A[k][j]; B[i][j] -= f * B[k][j]; }
            }
        }
    }
#pragma unroll
    for (int a = 0; a < 8; ++a) {
        union { float4 f; __half2 h[4]; } u;
#pragma unroll
        for (int k = 0; k < 4; ++k) u.h[k] = __floats2half2_rn(B[a][2*k], B[a][2*k+1]);
        *(float4*)(dinv + ((size_t)m << 6) + (a << 3)) = u.f;
    }
}

// w = A z  (fp16 gather mirror zh). Wave/node grid-strided; unrolled x2.
// Fused dot: mu = z.w -> slots.
__global__ __launch_bounds__(256) void k_mv(const __half* __restrict__ rh,
                                            float* __restrict__ wv,
                                            const int* __restrict__ off,
                                            const int* __restrict__ nbA,
                                            const __half* __restrict__ Wc,
                                            const __half* __restrict__ diag,
                                            float* __restrict__ mu) {
    int lane = threadIdx.x & 63;
    int g = lane >> 3, a = lane & 7;
    int waveId = (blockIdx.x * blockDim.x + threadIdx.x) >> 6;
    int nWaves = (gridDim.x * blockDim.x) >> 6;
    float mu0 = 0.f, mu1 = 0.f;
    for (int m = waveId; m < M_NODES; m += nWaves) {
        int beg = off[m], end = off[m + 1];
        float acc0 = 0.f, acc1 = 0.f;
        int i = beg + g;
        for (; i + 8 < end; i += 16) {
            int nA = nbA[i];
            int nB = nbA[i + 8];
            union { float4 f; __half2 h[4]; } uA, uB, rA0, rA1, rB0, rB1;
            uA.f = *(const float4*)(Wc + ((size_t)i << 6) + (a << 3));
            uB.f = *(const float4*)(Wc + ((size_t)(i + 8) << 6) + (a << 3));
            rA0.f = *(const float4*)(rh + (nA << 4));
            rA1.f = *(const float4*)(rh + (nA << 4) + 8);
            rB0.f = *(const float4*)(rh + (nB << 4));
            rB1.f = *(const float4*)(rh + (nB << 4) + 8);
            float2 wA0 = __half22float2(uA.h[0]);
            float2 wA1 = __half22float2(uA.h[1]);
            float2 wA2 = __half22float2(uA.h[2]);
            float2 wA3 = __half22float2(uA.h[3]);
            float2 a00 = __half22float2(rA0.h[0]);
            float2 a01 = __half22float2(rA0.h[1]);
            float2 a02 = __half22float2(rA0.h[2]);
            float2 a03 = __half22float2(rA0.h[3]);
            float2 a10 = __half22float2(rA1.h[0]);
            float2 a11 = __half22float2(rA1.h[1]);
            float2 a12 = __half22float2(rA1.h[2]);
            float2 a13 = __half22float2(rA1.h[3]);
            acc0 += wA0.x*a00.x + wA0.y*a00.y + wA1.x*a01.x + wA1.y*a01.y
                  + wA2.x*a02.x + wA2.y*a02.y + wA3.x*a03.x + wA3.y*a03.y;
            acc1 += wA0.x*a10.x + wA0.y*a10.y + wA1.x*a11.x + wA1.y*a11.y
                  + wA2.x*a12.x + wA2.y*a12.y + wA3.x*a13.x + wA3.y*a13.y;
            float2 wB0 = __half22float2(uB.h[0]);
            float2 wB1 = __half22float2(uB.h[1]);
            float2 wB2 = __half22float2(uB.h[2]);
            float2 wB3 = __half22float2(uB.h[3]);
            float2 b00 = __half22float2(rB0.h[0]);
            float2 b01 = __half22float2(rB0.h[1]);
            float2 b02 = __half22float2(rB0.h[2]);
            float2 b03 = __half22float2(rB0.h[3]);
            float2 b10 = __half22float2(rB1.h[0]);
            float2 b11 = __half22float2(rB1.h[1]);
            float2 b12 = __half22float2(rB1.h[2]);
            float2 b13 = __half22float2(rB1.h[3]);
            acc0 += wB0.x*b00.x + wB0.y*b00.y + wB1.x*b01.x + wB1.y*b01.y
                  + wB2.x*b02.x + wB2.y*b02.y + wB3.x*b03.x + wB3.y*b03.y;
            acc1 += wB0.x*b10.x + wB0.y*b10.y + wB1.x*b11.x + wB1.y*b11.y
                  + wB2.x*b12.x + wB2.y*b12.y + wB3.x*b13.x + wB3.y*b13.y;
        }
        if (i < end) {
            int n = nbA[i];
            union { float4 f; __half2 h[4]; } u, r0, r1;
            u.f = *(const float4*)(Wc + ((size_t)i << 6) + (a << 3));
            r0.f = *(const float4*)(rh + (n << 4));
            r1.f = *(const float4*)(rh + (n << 4) + 8);
            float2 w0 = __half22float2(u.h[0]);
            float2 w1 = __half22float2(u.h[1]);
            float2 w2 = __half22float2(u.h[2]);
            float2 w3 = __half22float2(u.h[3]);
            float2 c00 = __half22float2(r0.h[0]);
            float2 c01 = __half22float2(r0.h[1]);
            float2 c02 = __half22float2(r0.h[2]);
            float2 c03 = __half22float2(r0.h[3]);
            float2 c10 = __half22float2(r1.h[0]);
            float2 c11 = __half22float2(r1.h[1]);
            float2 c12 = __half22float2(r1.h[2]);
            float2 c13 = __half22float2(r1.h[3]);
            acc0 += w0.x*c00.x + w0.y*c00.y + w1.x*c01.x + w1.y*c01.y
                  + w2.x*c02.x + w2.y*c02.y + w3.x*c03.x + w3.y*c03.y;
            acc1 += w0.x*c10.x + w0.y*c10.y + w1.x*c11.x + w1.y*c11.y
                  + w2.x*c12.x + w2.y*c12.y + w3.x*c13.x + w3.y*c13.y;
        }
        acc0 += __shfl_xor(acc0, 8, 64);  acc1 += __shfl_xor(acc1, 8, 64);
        acc0 += __shfl_xor(acc0, 16, 64); acc1 += __shfl_xor(acc1, 16, 64);
        acc0 += __shfl_xor(acc0, 32, 64); acc1 += __shfl_xor(acc1, 32, 64);
        if (g < 2) {
            union { float4 f; __half2 h[4]; } ur, ud;
            ur.f = *(const float4*)(rh + (m << 4) + (g << 3));
            ud.f = *(const float4*)(diag + ((size_t)m << 6) + (a << 3));
            float rm[8];
            float2 t;
            t = __half22float2(ur.h[0]); rm[0] = t.x; rm[1] = t.y;
            t = __half22float2(ur.h[1]); rm[2] = t.x; rm[3] = t.y;
            t = __half22float2(ur.h[2]); rm[4] = t.x; rm[5] = t.y;
            t = __half22float2(ur.h[3]); rm[6] = t.x; rm[7] = t.y;
            float2 g0 = __half22float2(ud.h[0]);
            float2 g1 = __half22float2(ud.h[1]);
            float2 g2 = __half22float2(ud.h[2]);
            float2 g3 = __half22float2(ud.h[3]);
            float acc = g ? acc1 : acc0;
            float w = g0.x*rm[0] + g0.y*rm[1] + g1.x*rm[2] + g1.y*rm[3]
                    + g2.x*rm[4] + g2.y*rm[5] + g3.x*rm[6] + g3.y*rm[7] - acc;
            wv[(m << 4) + (g << 3) + a] = w;
            float ra = rm[a];
            if (g == 0) mu0 += ra * w; else mu1 += ra * w;
        }
    }
    blockReduceAdd2(mu0, mu1, mu);
}

// init: thread per (m,b). r = b - w; x = b; z = Dinv r; zh; rho0 = r.z
__global__ __launch_bounds__(256) void k_init0(const float4* __restrict__ c0,
                                               const float4* __restrict__ w,
                                               float4* __restrict__ r,
                                               float4* __restrict__ x,
                                               float4* __restrict__ z,
                                               __half* __restrict__ zh,
                                               const __half* __restrict__ dinv,
                                               float* __restrict__ rho0) {
    int u = blockIdx.x * blockDim.x + threadIdx.x;
    float s0 = 0.f, s1 = 0.f;
    if (u < M_NODES * 2) {
        int m = u >> 1, bb = u & 1;
        int f4 = (m << 2) + (bb << 1);
        float4 b0 = c0[bb * (PER_B / 4) + (m << 1)];
        float4 b1 = c0[bb * (PER_B / 4) + (m << 1) + 1];
        float4 w0 = w[f4], w1 = w[f4 + 1];
        float rr[8];
        rr[0] = b0.x - w0.x; rr[1] = b0.y - w0.y; rr[2] = b0.z - w0.z; rr[3] = b0.w - w0.w;
        rr[4] = b1.x - w1.x; rr[5] = b1.y - w1.y; rr[6] = b1.z - w1.z; rr[7] = b1.w - w1.w;
        x[f4] = b0; x[f4 + 1] = b1;
        r[f4] = make_float4(rr[0], rr[1], rr[2], rr[3]);
        r[f4 + 1] = make_float4(rr[4], rr[5], rr[6], rr[7]);
        float zz[8];
        const __half* dv = dinv + ((size_t)m << 6);
#pragma unroll
        for (int a = 0; a < 8; ++a) {
            union { float4 f; __half2 h[4]; } u2;
            u2.f = *(const float4*)(dv + (a << 3));
            float2 t0 = __half22float2(u2.h[0]);
            float2 t1 = __half22float2(u2.h[1]);
            float2 t2 = __half22float2(u2.h[2]);
            float2 t3 = __half22float2(u2.h[3]);
            zz[a] = t0.x*rr[0] + t0.y*rr[1] + t1.x*rr[2] + t1.y*rr[3]
                  + t2.x*rr[4] + t2.y*rr[5] + t3.x*rr[6] + t3.y*rr[7];
        }
        float4 z0 = make_float4(zz[0], zz[1], zz[2], zz[3]);
        float4 z1 = make_float4(zz[4], zz[5], zz[6], zz[7]);
        z[f4] = z0; z[f4 + 1] = z1;
        writeHalf4(zh, f4, z0);
        writeHalf4(zh, f4 + 1, z1);
        float d = rr[0]*zz[0] + rr[1]*zz[1] + rr[2]*zz[2] + rr[3]*zz[3]
                + rr[4]*zz[4] + rr[5]*zz[5] + rr[6]*zz[6] + rr[7]*zz[7];
        if (bb == 0) s0 = d; else s1 = d;
    }
    blockReduceAdd2(s0, s1, rho0);
}

// C-G PCG update: thread per (m,b), grid-stride. Scalars once/block.
// p = z + beta p; q = w + beta q; x += alpha p; r -= alpha q;
// z = Dinv r (+zh); rho_next = r.z. Last iter: only out = x.
__global__ __launch_bounds__(256) void k_axpy(float4* __restrict__ x,
                                              float4* __restrict__ r,
                                              float4* __restrict__ z,
                                              __half* __restrict__ zh,
                                              float4* __restrict__ p,
                                              float4* __restrict__ q,
                                              const float4* __restrict__ w,
                                              const __half* __restrict__ dinv,
                                              const float* __restrict__ rho_s,
                                              const float* __restrict__ mu_s,
                                              float* __restrict__ fin,
                                              float* __restrict__ rho_next,
                                              int j, int last,
                                              float4* __restrict__ out) {
    __shared__ float sc[4];
    if (threadIdx.x == 0) {
        float2 rho = sumSlots(rho_s);
        float2 mu  = sumSlots(mu_s);
        float b0, b1, al0, al1;
        if (j == 0) {
            b0 = b1 = 0.0f;
            al0 = rho.x / (mu.x + EPSF);
            al1 = rho.y / (mu.y + EPSF);
        } else {
            float ap0 = fin[4*(j-1)+0], ap1 = fin[4*(j-1)+1];
            float rp0 = fin[4*(j-1)+2], rp1 = fin[4*(j-1)+3];
            b0 = rho.x / (rp0 + EPSF);
            b1 = rho.y / (rp1 + EPSF);
            al0 = rho.x / (mu.x - b0 * rho.x / (ap0 + EPSF) + EPSF);
            al1 = rho.y / (mu.y - b1 * rho.y / (ap1 + EPSF) + EPSF);
        }
        if (!last && blockIdx.x == 0) {
            fin[4*j] = al0; fin[4*j+1] = al1; fin[4*j+2] = rho.x; fin[4*j+3] = rho.y;
        }
        sc[0] = al0; sc[1] = al1; sc[2] = b0; sc[3] = b1;
    }
    __syncthreads();
    float al0 = sc[0], al1 = sc[1], b0s = sc[2], b1s = sc[3];
    float s0 = 0.f, s1 = 0.f;
    for (int u = blockIdx.x * blockDim.x + threadIdx.x; u < M_NODES * 2;
         u += gridDim.x * blockDim.x) {
        int m = u >> 1, bb = u & 1;
        int f4 = (m << 2) + (bb << 1);
        float be = bb ? b1s : b0s;
        float al = bb ? al1 : al0;
        float4 zv0 = z[f4], zv1 = z[f4 + 1];
        float4 wv0 = w[f4], wv1 = w[f4 + 1];
        float4 pn0, pn1, qn0, qn1;
        if (j == 0) { pn0 = zv0; pn1 = zv1; qn0 = wv0; qn1 = wv1; }
        else {
            float4 pv0 = p[f4], pv1 = p[f4 + 1];
            float4 qv0 = q[f4], qv1 = q[f4 + 1];
            pn0 = make_float4(zv0.x + be*pv0.x, zv0.y + be*pv0.y, zv0.z + be*pv0.z, zv0.w + be*pv0.w);
            pn1 = make_float4(zv1.x + be*pv1.x, zv1.y + be*pv1.y, zv1.z + be*pv1.z, zv1.w + be*pv1.w);
            qn0 = make_float4(wv0.x + be*qv0.x, wv0.y + be*qv0.y, wv0.z + be*qv0.z, wv0.w + be*qv0.w);
            qn1 = make_float4(wv1.x + be*qv1.x, wv1.y + be*qv1.y, wv1.z + be*qv1.z, wv1.w + be*qv1.w);
        }
        float4 xv0 = x[f4], xv1 = x[f4 + 1];
        float4 xn0 = make_float4(xv0.x + al*pn0.x, xv0.y + al*pn0.y, xv0.z + al*pn0.z, xv0.w + al*pn0.w);
        float4 xn1 = make_float4(xv1.x + al*pn1.x, xv1.y + al*pn1.y, xv1.z + al*pn1.z, xv1.w + al*pn1.w);
        if (last) {
            out[bb * (PER_B / 4) + (m << 1)] = xn0;
            out[bb * (PER_B / 4) + (m << 1) + 1] = xn1;
        } else {
            float4 rv0 = r[f4], rv1 = r[f4 + 1];
            float rr[8];
            rr[0] = rv0.x - al*qn0.x; rr[1] = rv0.y - al*qn0.y;
            rr[2] = rv0.z - al*qn0.z; rr[3] = rv0.w - al*qn0.w;
            rr[4] = rv1.x - al*qn1.x; rr[5] = rv1.y - al*qn1.y;
            rr[6] = rv1.z - al*qn1.z; rr[7] = rv1.w - al*qn1.w;
            x[f4] = xn0; x[f4 + 1] = xn1;
            r[f4] = make_float4(rr[0], rr[1], rr[2], rr[3]);
            r[f4 + 1] = make_float4(rr[4], rr[5], rr[6], rr[7]);
            p[f4] = pn0; p[f4 + 1] = pn1;
            q[f4] = qn0; q[f4 + 1] = qn1;
            float zz[8];
            const __half* dv = dinv + ((size_t)m << 6);
#pragma unroll
            for (int a = 0; a < 8; ++a) {
                union { float4 f; __half2 h[4]; } u2;
                u2.f = *(const float4*)(dv + (a << 3));
                float2 t0 = __half22float2(u2.h[0]);
                float2 t1 = __half22float2(u2.h[1]);
                float2 t2 = __half22float2(u2.h[2]);
                float2 t3 = __half22float2(u2.h[3]);
                zz[a] = t0.x*rr[0] + t0.y*rr[1] + t1.x*rr[2] + t1.y*rr[3]
                      + t2.x*rr[4] + t2.y*rr[5] + t3.x*rr[6] + t3.y*rr[7];
            }
            float4 z0 = make_float4(zz[0], zz[1], zz[2], zz[3]);
            float4 z1 = make_float4(zz[4], zz[5], zz[6], zz[7]);
            z[f4] = z0; z[f4 + 1] = z1;
            writeHalf4(zh, f4, z0);
            writeHalf4(zh, f4 + 1, z1);
            float d = rr[0]*zz[0] + rr[1]*zz[1] + rr[2]*zz[2] + rr[3]*zz[3]
                    + rr[4]*zz[4] + rr[5]*zz[5] + rr[6]*zz[6] + rr[7]*zz[7];
            if (bb == 0) s0 += d; else s1 += d;
        }
    }
    if (!last) blockReduceAdd2(s0, s1, rho_next);
}

extern "C" void kernel_launch(void* const* d_in, const int* in_sizes, int n_in,
                              void* d_out, int out_size, void* d_ws, size_t ws_size,
                              hipStream_t stream) {
    const float* c0 = (const float*)d_in[0];
    const int* src  = (const int*)d_in[1];
    const int* dst  = (const int*)d_in[2];
    const float* Rs = (const float*)d_in[3];
    const float* Rd = (const float*)d_in[4];

    char* wsp = (char*)d_ws;
    size_t o = 0;
    auto alloc = [&](size_t bytes) { char* c = wsp + o; o = (o + bytes + 255) & ~(size_t)255; return c; };
    float* r      = (float*)alloc(VEC_N * 4);
    float* wv     = (float*)alloc(VEC_N * 4);
    float* p      = (float*)alloc(VEC_N * 4);
    float* q      = (float*)alloc(VEC_N * 4);
    float* x      = (float*)alloc(VEC_N * 4);
    float* z      = (float*)alloc(VEC_N * 4);
    __half* zh    = (__half*)alloc(VEC_N * 2);
    __half* bh    = (__half*)alloc(VEC_N * 2);
    float* scal   = (float*)alloc(4096 * 4);
    int*   cnt    = (int*)alloc(M_NODES * 4);
    int*   offa   = (int*)alloc((M_NODES + 1) * 4);
    int*   cursor = (int*)alloc(M_NODES * 4);
    int*   partial= (int*)alloc(M_NODES * 4);
    int*   btot   = (int*)alloc(SCB * 4);
    int*   boff   = (int*)alloc(SCB * 4);
    int*   pos0   = (int*)alloc(E_EDGES * 4);
    int*   pos1   = (int*)alloc(E_EDGES * 4);
    int*   wk     = (int*)alloc(N_INC * 4);
    int*   nb     = (int*)alloc(N_INC * 4);
    __half* diag  = (__half*)alloc((size_t)M_NODES * 64 * 2);
    __half* dinv  = (__half*)alloc((size_t)M_NODES * 64 * 2);
    __half* Wc    = (__half*)alloc((size_t)N_INC * 64 * 2);
    size_t ghBytes = (size_t)N_INC * 64 * 2;
    int haveGH = (o + ghBytes) <= ws_size;
    __half* GHc = haveGH ? (__half*)alloc(ghBytes) : (__half*)Wc;

    const int BLK = 256;
    const int grid_v  = (N4 + BLK - 1) / BLK;
    const int grid_e  = (E_EDGES + BLK - 1) / BLK;
    const int grid_e8 = (E_EDGES * 8 + BLK - 1) / BLK;
    const int grid_m8 = (M_NODES * 8 + BLK - 1) / BLK;
    const int grid_mw = (M_NODES * 64 + BLK - 1) / BLK;
    const int grid_u  = (M_NODES * 2 + BLK - 1) / BLK;
    const int MVB     = 2048;
    const int AXB     = 392;

    float* RHO = scal;             // RHO(t) = scal + 64*t
    float* MU  = scal + 1024;      // MU(t)  = scal + 1024 + 64*t
    float* FIN = scal + 3968;

    // ---- precompute (rebuilt every call) ----
    k_prolog<<<grid_v, BLK, 0, stream>>>(scal, cnt, (const float4*)c0, bh);
    k_hist<<<grid_e, BLK, 0, stream>>>(src, dst, cnt);
    k_scanA<<<SCB, SCT, 0, stream>>>(cnt, partial, btot);
    k_scanB<<<1, SCT, 0, stream>>>(btot, boff, offa);
    k_scanC<<<SCB, SCT, 0, stream>>>(partial, boff, offa, cursor);
    k_scatter<<<grid_e, BLK, 0, stream>>>(src, dst, cursor, pos0, pos1, nb, wk);
    k_buildC<<<grid_e8, BLK, 0, stream>>>(Rs, Rd, pos0, pos1, Wc, GHc, haveGH);
    if (haveGH)
        k_diagS<<<grid_mw, BLK, 0, stream>>>(offa, GHc, diag);
    else
        k_diagR<<<grid_m8, BLK, 0, stream>>>(offa, wk, Rs, Rd, diag);
    k_dinv<<<(M_NODES + 63) / 64, 64, 0, stream>>>(diag, dinv);

    // ---- init: w = A b; r,x,z,zh,rho0 ----
    k_mv<<<MVB, BLK, 0, stream>>>(bh, wv, offa, nb, Wc, diag, MU + 64 * 12);
    k_init0<<<grid_u, BLK, 0, stream>>>((const float4*)c0, (const float4*)wv,
                                        (float4*)r, (float4*)x, (float4*)z, zh,
                                        dinv, RHO);

    // ---- C-G PCG: 2 kernels/iter, matvec on zh ----
    for (int t = 0; t < CG_ITERS; ++t) {
        k_mv<<<MVB, BLK, 0, stream>>>(zh, wv, offa, nb, Wc, diag, MU + 64 * t);
        k_axpy<<<AXB, BLK, 0, stream>>>((float4*)x, (float4*)r, (float4*)z, zh,
                                        (float4*)p, (float4*)q, (const float4*)wv,
                                        dinv, RHO + 64 * t, MU + 64 * t, FIN,
                                        RHO + 64 * (t + 1), t,
                                        (t == CG_ITERS - 1) ? 1 : 0,
                                        (float4*)d_out);
    }
}

// Round 17
// 543.167 us; speedup vs baseline: 4.5942x; 1.1041x over previous
//
#include <hip/hip_runtime.h>
#include <hip/hip_fp16.h>

#define E_EDGES   400000
#define M_NODES   50000
#define N_INC     800000
#define PER_B     400000
#define VEC_N     800000
#define N4        200000
#define CG_ITERS  4
#define EPSF      1e-12f

// scal (4096 floats): 32 slot-pairs (64 floats) per instance.
//   RHO(t) = scal + 64*t           t=0..12
//   MU(t)  = scal + 1024 + 64*t    t=0..12  (t=12 = init-mv scratch)
//   fin    = scal + 3968 : fin[4t+0/1]=alpha_t(b0/b1), fin[4t+2/3]=rho_t(b0/b1)

__device__ __forceinline__ float waveReduce(float v) {
#pragma unroll
    for (int off = 32; off > 0; off >>= 1)
        v += __shfl_down(v, off, 64);
    return v;
}

__device__ __forceinline__ void blockReduceAdd2(float d0, float d1, float* __restrict__ base) {
    __shared__ float red[8];
    d0 = waveReduce(d0);
    d1 = waveReduce(d1);
    int w = threadIdx.x >> 6, lane = threadIdx.x & 63;
    if (lane == 0) { red[2*w] = d0; red[2*w+1] = d1; }
    __syncthreads();
    if (threadIdx.x == 0) {
        float t0 = red[0] + red[2] + red[4] + red[6];
        float t1 = red[1] + red[3] + red[5] + red[7];
        int s = (blockIdx.x & 31) << 1;
        atomicAdd(&base[s], t0);
        atomicAdd(&base[s + 1], t1);
    }
}

__device__ __forceinline__ float2 sumSlots(const float* __restrict__ base) {
    float a = 0.0f, b = 0.0f;
#pragma unroll
    for (int k = 0; k < 32; ++k) { a += base[2*k]; b += base[2*k+1]; }
    return make_float2(a, b);
}

__device__ __forceinline__ void writeHalf4(__half* __restrict__ rh, int i4, float4 v) {
    union { float2 f2; __half2 h[2]; } u;
    u.h[0] = __floats2half2_rn(v.x, v.y);
    u.h[1] = __floats2half2_rn(v.z, v.w);
    *(float2*)(rh + (i4 << 2)) = u.f2;
}

// prologue: zero scal + cnt, and bh = fp16(interleave(c0)) — one launch
__global__ void k_prolog(float* __restrict__ s, int* __restrict__ cnt,
                         const float4* __restrict__ src, __half* __restrict__ ilh) {
    int i = blockIdx.x * blockDim.x + threadIdx.x;
    if (i < 4096) s[i] = 0.0f;
    if (i < M_NODES) cnt[i] = 0;
    if (i < N4) {
        int b = i / (PER_B / 4);
        int rem = i - b * (PER_B / 4);
        int m = rem >> 1, half = rem & 1;
        int d = (m << 2) + (b << 1) + half;
        writeHalf4(ilh, d, src[i]);
    }
}

__global__ void k_hist(const int* __restrict__ src, const int* __restrict__ dst,
                       int* __restrict__ cnt) {
    int e = blockIdx.x * blockDim.x + threadIdx.x;
    if (e < E_EDGES) {
        atomicAdd(&cnt[src[e]], 1);
        atomicAdd(&cnt[dst[e]], 1);
    }
}

// ---- multi-block exclusive scan ----
#define SCT 256
#define SCB ((M_NODES + SCT - 1) / SCT)

__global__ __launch_bounds__(SCT) void k_scanA(const int* __restrict__ cnt,
                                               int* __restrict__ partial,
                                               int* __restrict__ btot) {
    __shared__ int sh[SCT];
    int i = blockIdx.x * SCT + threadIdx.x;
    int v = (i < M_NODES) ? cnt[i] : 0;
    sh[threadIdx.x] = v;
    __syncthreads();
    for (int st = 1; st < SCT; st <<= 1) {
        int t = (threadIdx.x >= st) ? sh[threadIdx.x - st] : 0;
        __syncthreads();
        sh[threadIdx.x] += t;
        __syncthreads();
    }
    if (i < M_NODES) partial[i] = sh[threadIdx.x] - v;
    if (threadIdx.x == SCT - 1) btot[blockIdx.x] = sh[SCT - 1];
}

__global__ __launch_bounds__(SCT) void k_scanB(const int* __restrict__ btot,
                                               int* __restrict__ boff,
                                               int* __restrict__ off) {
    __shared__ int sh[SCT];
    int v = (threadIdx.x < SCB) ? btot[threadIdx.x] : 0;
    sh[threadIdx.x] = v;
    __syncthreads();
    for (int st = 1; st < SCT; st <<= 1) {
        int t = (threadIdx.x >= st) ? sh[threadIdx.x - st] : 0;
        __syncthreads();
        sh[threadIdx.x] += t;
        __syncthreads();
    }
    if (threadIdx.x < SCB) boff[threadIdx.x] = sh[threadIdx.x] - v;
    if (threadIdx.x == SCT - 1) off[M_NODES] = sh[SCT - 1];
}

__global__ __launch_bounds__(SCT) void k_scanC(const int* __restrict__ partial,
                                               const int* __restrict__ boff,
                                               int* __restrict__ off,
                                               int* __restrict__ cursor) {
    int i = blockIdx.x * SCT + threadIdx.x;
    if (i < M_NODES) {
        int o = boff[blockIdx.x] + partial[i];
        off[i] = o; cursor[i] = o;
    }
}

__global__ void k_scatter(const int* __restrict__ src, const int* __restrict__ dst,
                          int* __restrict__ cursor, int* __restrict__ pos0,
                          int* __restrict__ pos1, int* __restrict__ nb,
                          int* __restrict__ wk) {
    int e = blockIdx.x * blockDim.x + threadIdx.x;
    if (e < E_EDGES) {
        int s = src[e], t = dst[e];
        int p0 = atomicAdd(&cursor[s], 1);
        pos0[e] = p0; nb[p0] = t; wk[p0] = e;
        int p1 = atomicAdd(&cursor[t], 1);
        pos1[e] = p1; nb[p1] = s; wk[p1] = e + E_EDGES;
    }
}

// 8 lanes/edge, coalesced sequential R reads; scatter-write 128B blocks to CSR slots.
__global__ __launch_bounds__(256) void k_buildC(const float* __restrict__ Rs,
                                                const float* __restrict__ Rd,
                                                const int* __restrict__ pos0,
                                                const int* __restrict__ pos1,
                                                __half* __restrict__ Wc,
                                                __half* __restrict__ GHc, int haveGH) {
    int gt = blockIdx.x * blockDim.x + threadIdx.x;
    int e = gt >> 3, a = gt & 7;
    if (e >= E_EDGES) return;
    const float* rs = Rs + ((size_t)e << 6);
    const float* rd = Rd + ((size_t)e << 6);
    float C[8], Ct[8], G[8], H[8];
#pragma unroll
    for (int j = 0; j < 8; ++j) { C[j] = 0; Ct[j] = 0; G[j] = 0; H[j] = 0; }
#pragma unroll
    for (int c = 0; c < 8; ++c) {
        float xs = rs[c * 8 + a];
        float xd = rd[c * 8 + a];
        float4 s0 = *(const float4*)(rs + c * 8);
        float4 s1 = *(const float4*)(rs + c * 8 + 4);
        float4 d0 = *(const float4*)(rd + c * 8);
        float4 d1 = *(const float4*)(rd + c * 8 + 4);
        C[0] += xs * d0.x; C[1] += xs * d0.y; C[2] += xs * d0.z; C[3] += xs * d0.w;
        C[4] += xs * d1.x; C[5] += xs * d1.y; C[6] += xs * d1.z; C[7] += xs * d1.w;
        Ct[0] += xd * s0.x; Ct[1] += xd * s0.y; Ct[2] += xd * s0.z; Ct[3] += xd * s0.w;
        Ct[4] += xd * s1.x; Ct[5] += xd * s1.y; Ct[6] += xd * s1.z; Ct[7] += xd * s1.w;
        G[0] += xs * s0.x; G[1] += xs * s0.y; G[2] += xs * s0.z; G[3] += xs * s0.w;
        G[4] += xs * s1.x; G[5] += xs * s1.y; G[6] += xs * s1.z; G[7] += xs * s1.w;
        H[0] += xd * d0.x; H[1] += xd * d0.y; H[2] += xd * d0.z; H[3] += xd * d0.w;
        H[4] += xd * d1.x; H[5] += xd * d1.y; H[6] += xd * d1.z; H[7] += xd * d1.w;
    }
    size_t s0o = (size_t)pos0[e] << 6;
    size_t s1o = (size_t)pos1[e] << 6;
    union { float4 f; __half2 h[4]; } u;
#pragma unroll
    for (int k = 0; k < 4; ++k) u.h[k] = __floats2half2_rn(C[2*k], C[2*k+1]);
    *(float4*)(Wc + s0o + (a << 3)) = u.f;
#pragma unroll
    for (int k = 0; k < 4; ++k) u.h[k] = __floats2half2_rn(Ct[2*k], Ct[2*k+1]);
    *(float4*)(Wc + s1o + (a << 3)) = u.f;
    if (haveGH) {
#pragma unroll
        for (int k = 0; k < 4; ++k) u.h[k] = __floats2half2_rn(G[2*k], G[2*k+1]);
        *(float4*)(GHc + s0o + (a << 3)) = u.f;
#pragma unroll
        for (int k = 0; k < 4; ++k) u.h[k] = __floats2half2_rn(H[2*k], H[2*k+1]);
        *(float4*)(GHc + s1o + (a << 3)) = u.f;
    }
}

// diag (fp16) from CSR-streamed GH: wave per node.
__global__ __launch_bounds__(256) void k_diagS(const int* __restrict__ off,
                                               const __half* __restrict__ GHc,
                                               __half* __restrict__ diag) {
    int wave = (blockIdx.x * blockDim.x + threadIdx.x) >> 6;
    int lane = threadIdx.x & 63;
    int g = lane >> 3, a = lane & 7;
    int m = wave;
    if (m >= M_NODES) return;
    float D[8];
#pragma unroll
    for (int j = 0; j < 8; ++j) D[j] = 0.0f;
    int beg = off[m], end = off[m + 1];
    for (int i = beg + g; i < end; i += 8) {
        union { float4 f; __half2 h[4]; } u;
        u.f = *(const float4*)(GHc + ((size_t)i << 6) + (a << 3));
        float2 w0 = __half22float2(u.h[0]);
        float2 w1 = __half22float2(u.h[1]);
        float2 w2 = __half22float2(u.h[2]);
        float2 w3 = __half22float2(u.h[3]);
        D[0] += w0.x; D[1] += w0.y; D[2] += w1.x; D[3] += w1.y;
        D[4] += w2.x; D[5] += w2.y; D[6] += w3.x; D[7] += w3.y;
    }
#pragma unroll
    for (int j = 0; j < 8; ++j) {
        D[j] += __shfl_xor(D[j], 8, 64);
        D[j] += __shfl_xor(D[j], 16, 64);
        D[j] += __shfl_xor(D[j], 32, 64);
    }
    if (g == 0) {
        D[a] += 1.0f;
        union { float4 f; __half2 h[4]; } u;
#pragma unroll
        for (int k = 0; k < 4; ++k) u.h[k] = __floats2half2_rn(D[2*k], D[2*k+1]);
        *(float4*)(diag + ((size_t)m << 6) + (a << 3)) = u.f;
    }
}

// fallback diag straight from R (runs once)
__global__ void k_diagR(const int* __restrict__ off, const int* __restrict__ wk,
                        const float* __restrict__ Rs, const float* __restrict__ Rd,
                        __half* __restrict__ diag) {
    int gt = blockIdx.x * blockDim.x + threadIdx.x;
    int m = gt >> 3, a = gt & 7;
    if (m >= M_NODES) return;
    float D[8];
#pragma unroll
    for (int j = 0; j < 8; ++j) D[j] = 0.0f;
    int beg = off[m], end = off[m + 1];
    for (int i = beg; i < end; ++i) {
        int k = wk[i];
        int side = (k >= E_EDGES);
        int e = k - (side ? E_EDGES : 0);
        const float* R = (side ? Rd : Rs) + ((size_t)e << 6);
#pragma unroll
        for (int c = 0; c < 8; ++c) {
            float xa = R[c * 8 + a];
            float4 y0 = *(const float4*)(R + c * 8);
            float4 y1 = *(const float4*)(R + c * 8 + 4);
            D[0] += xa * y0.x; D[1] += xa * y0.y; D[2] += xa * y0.z; D[3] += xa * y0.w;
            D[4] += xa * y1.x; D[5] += xa * y1.y; D[6] += xa * y1.z; D[7] += xa * y1.w;
        }
    }
    D[a] += 1.0f;
    union { float4 f; __half2 h[4]; } u;
#pragma unroll
    for (int k = 0; k < 4; ++k) u.h[k] = __floats2half2_rn(D[2*k], D[2*k+1]);
    *(float4*)(diag + ((size_t)m << 6) + (a << 3)) = u.f;
}

// one-time: Dinv[m] = inverse of 8x8 diag block (Gauss-Jordan, SPD, no pivoting)
__global__ __launch_bounds__(64) void k_dinv(const __half* __restrict__ diag,
                                             __half* __restrict__ dinv) {
    int m = blockIdx.x * blockDim.x + threadIdx.x;
    if (m >= M_NODES) return;
    float A[8][8], B[8][8];
#pragma unroll
    for (int a = 0; a < 8; ++a) {
        union { float4 f; __half2 h[4]; } u;
        u.f = *(const float4*)(diag + ((size_t)m << 6) + (a << 3));
#pragma unroll
        for (int k = 0; k < 4; ++k) {
            float2 t = __half22float2(u.h[k]);
            A[a][2*k] = t.x; A[a][2*k+1] = t.y;
        }
#pragma unroll
        for (int j = 0; j < 8; ++j) B[a][j] = (a == j) ? 1.0f : 0.0f;
    }
#pragma unroll
    for (int k = 0; k < 8; ++k) {
        float piv = 1.0f / A[k][k];
#pragma unroll
        for (int j = 0; j < 8; ++j) { A[k][j] *= piv; B[k][j] *= piv; }
#pragma unroll
        for (int i = 0; i < 8; ++i) {
            if (i != k) {
                float f = A[i][k];
#pragma unroll
                for (int j = 0; j < 8; ++j) { A[i][j] -= f * A[k][j]; B[i][j] -= f * B[k][j]; }
            }
        }
    }
#pragma unroll
    for (int a = 0; a < 8; ++a) {
        union { float4 f; __half2 h[4]; } u;
#pragma unroll
        for (int k = 0; k < 4; ++k) u.h[k] = __floats2half2_rn(B[a][2*k], B[a][2*k+1]);
        *(float4*)(dinv + ((size_t)m << 6) + (a << 3)) = u.f;
    }
}

// w = A z  (fp16 gather mirror zh). Wave/node grid-strided; unrolled x2.
// Fused dot: mu = z.w -> slots.
__global__ __launch_bounds__(256) void k_mv(const __half* __restrict__ rh,
                                            float* __restrict__ wv,
                                            const int* __restrict__ off,
                                            const int* __restrict__ nbA,
                                            const __half* __restrict__ Wc,
                                            const __half* __restrict__ diag,
                                            float* __restrict__ mu) {
    int lane = threadIdx.x & 63;
    int g = lane >> 3, a = lane & 7;
    int waveId = (blockIdx.x * blockDim.x + threadIdx.x) >> 6;
    int nWaves = (gridDim.x * blockDim.x) >> 6;
    float mu0 = 0.f, mu1 = 0.f;
    for (int m = waveId; m < M_NODES; m += nWaves) {
        int beg = off[m], end = off[m + 1];
        float acc0 = 0.f, acc1 = 0.f;
        int i = beg + g;
        for (; i + 8 < end; i += 16) {
            int nA = nbA[i];
            int nB = nbA[i + 8];
            union { float4 f; __half2 h[4]; } uA, uB, rA0, rA1, rB0, rB1;
            uA.f = *(const float4*)(Wc + ((size_t)i << 6) + (a << 3));
            uB.f = *(const float4*)(Wc + ((size_t)(i + 8) << 6) + (a << 3));
            rA0.f = *(const float4*)(rh + (nA << 4));
            rA1.f = *(const float4*)(rh + (nA << 4) + 8);
            rB0.f = *(const float4*)(rh + (nB << 4));
            rB1.f = *(const float4*)(rh + (nB << 4) + 8);
            float2 wA0 = __half22float2(uA.h[0]);
            float2 wA1 = __half22float2(uA.h[1]);
            float2 wA2 = __half22float2(uA.h[2]);
            float2 wA3 = __half22float2(uA.h[3]);
            float2 a00 = __half22float2(rA0.h[0]);
            float2 a01 = __half22float2(rA0.h[1]);
            float2 a02 = __half22float2(rA0.h[2]);
            float2 a03 = __half22float2(rA0.h[3]);
            float2 a10 = __half22float2(rA1.h[0]);
            float2 a11 = __half22float2(rA1.h[1]);
            float2 a12 = __half22float2(rA1.h[2]);
            float2 a13 = __half22float2(rA1.h[3]);
            acc0 += wA0.x*a00.x + wA0.y*a00.y + wA1.x*a01.x + wA1.y*a01.y
                  + wA2.x*a02.x + wA2.y*a02.y + wA3.x*a03.x + wA3.y*a03.y;
            acc1 += wA0.x*a10.x + wA0.y*a10.y + wA1.x*a11.x + wA1.y*a11.y
                  + wA2.x*a12.x + wA2.y*a12.y + wA3.x*a13.x + wA3.y*a13.y;
            float2 wB0 = __half22float2(uB.h[0]);
            float2 wB1 = __half22float2(uB.h[1]);
            float2 wB2 = __half22float2(uB.h[2]);
            float2 wB3 = __half22float2(uB.h[3]);
            float2 b00 = __half22float2(rB0.h[0]);
            float2 b01 = __half22float2(rB0.h[1]);
            float2 b02 = __half22float2(rB0.h[2]);
            float2 b03 = __half22float2(rB0.h[3]);
            float2 b10 = __half22float2(rB1.h[0]);
            float2 b11 = __half22float2(rB1.h[1]);
            float2 b12 = __half22float2(rB1.h[2]);
            float2 b13 = __half22float2(rB1.h[3]);
            acc0 += wB0.x*b00.x + wB0.y*b00.y + wB1.x*b01.x + wB1.y*b01.y
                  + wB2.x*b02.x + wB2.y*b02.y + wB3.x*b03.x + wB3.y*b03.y;
            acc1 += wB0.x*b10.x + wB0.y*b10.y + wB1.x*b11.x + wB1.y*b11.y
                  + wB2.x*b12.x + wB2.y*b12.y + wB3.x*b13.x + wB3.y*b13.y;
        }
        if (i < end) {
            int n = nbA[i];
            union { float4 f; __half2 h[4]; } u, r0, r1;
            u.f = *(const float4*)(Wc + ((size_t)i << 6) + (a << 3));
            r0.f = *(const float4*)(rh + (n << 4));
            r1.f = *(const float4*)(rh + (n << 4) + 8);
            float2 w0 = __half22float2(u.h[0]);
            float2 w1 = __half22float2(u.h[1]);
            float2 w2 = __half22float2(u.h[2]);
            float2 w3 = __half22float2(u.h[3]);
            float2 c00 = __half22float2(r0.h[0]);
            float2 c01 = __half22float2(r0.h[1]);
            float2 c02 = __half22float2(r0.h[2]);
            float2 c03 = __half22float2(r0.h[3]);
            float2 c10 = __half22float2(r1.h[0]);
            float2 c11 = __half22float2(r1.h[1]);
            float2 c12 = __half22float2(r1.h[2]);
            float2 c13 = __half22float2(r1.h[3]);
            acc0 += w0.x*c00.x + w0.y*c00.y + w1.x*c01.x + w1.y*c01.y
                  + w2.x*c02.x + w2.y*c02.y + w3.x*c03.x + w3.y*c03.y;
            acc1 += w0.x*c10.x + w0.y*c10.y + w1.x*c11.x + w1.y*c11.y
                  + w2.x*c12.x + w2.y*c12.y + w3.x*c13.x + w3.y*c13.y;
        }
        acc0 += __shfl_xor(acc0, 8, 64);  acc1 += __shfl_xor(acc1, 8, 64);
        acc0 += __shfl_xor(acc0, 16, 64); acc1 += __shfl_xor(acc1, 16, 64);
        acc0 += __shfl_xor(acc0, 32, 64); acc1 += __shfl_xor(acc1, 32, 64);
        if (g < 2) {
            union { float4 f; __half2 h[4]; } ur, ud;
            ur.f = *(const float4*)(rh + (m << 4) + (g << 3));
            ud.f = *(const float4*)(diag + ((size_t)m << 6) + (a << 3));
            float rm[8];
            float2 t;
            t = __half22float2(ur.h[0]); rm[0] = t.x; rm[1] = t.y;
            t = __half22float2(ur.h[1]); rm[2] = t.x; rm[3] = t.y;
            t = __half22float2(ur.h[2]); rm[4] = t.x; rm[5] = t.y;
            t = __half22float2(ur.h[3]); rm[6] = t.x; rm[7] = t.y;
            float2 g0 = __half22float2(ud.h[0]);
            float2 g1 = __half22float2(ud.h[1]);
            float2 g2 = __half22float2(ud.h[2]);
            float2 g3 = __half22float2(ud.h[3]);
            float acc = g ? acc1 : acc0;
            float w = g0.x*rm[0] + g0.y*rm[1] + g1.x*rm[2] + g1.y*rm[3]
                    + g2.x*rm[4] + g2.y*rm[5] + g3.x*rm[6] + g3.y*rm[7] - acc;
            wv[(m << 4) + (g << 3) + a] = w;
            float ra = rm[a];
            if (g == 0) mu0 += ra * w; else mu1 += ra * w;
        }
    }
    blockReduceAdd2(mu0, mu1, mu);
}

// init: thread per (m,b). r = b - w; x = b; z = Dinv r; zh; rho0 = r.z
__global__ __launch_bounds__(256) void k_init0(const float4* __restrict__ c0,
                                               const float4* __restrict__ w,
                                               float4* __restrict__ r,
                                               float4* __restrict__ x,
                                               float4* __restrict__ z,
                                               __half* __restrict__ zh,
                                               const __half* __restrict__ dinv,
                                               float* __restrict__ rho0) {
    int u = blockIdx.x * blockDim.x + threadIdx.x;
    float s0 = 0.f, s1 = 0.f;
    if (u < M_NODES * 2) {
        int m = u >> 1, bb = u & 1;
        int f4 = (m << 2) + (bb << 1);
        float4 b0 = c0[bb * (PER_B / 4) + (m << 1)];
        float4 b1 = c0[bb * (PER_B / 4) + (m << 1) + 1];
        float4 w0 = w[f4], w1 = w[f4 + 1];
        float rr[8];
        rr[0] = b0.x - w0.x; rr[1] = b0.y - w0.y; rr[2] = b0.z - w0.z; rr[3] = b0.w - w0.w;
        rr[4] = b1.x - w1.x; rr[5] = b1.y - w1.y; rr[6] = b1.z - w1.z; rr[7] = b1.w - w1.w;
        x[f4] = b0; x[f4 + 1] = b1;
        r[f4] = make_float4(rr[0], rr[1], rr[2], rr[3]);
        r[f4 + 1] = make_float4(rr[4], rr[5], rr[6], rr[7]);
        float zz[8];
        const __half* dv = dinv + ((size_t)m << 6);
#pragma unroll
        for (int a = 0; a < 8; ++a) {
            union { float4 f; __half2 h[4]; } u2;
            u2.f = *(const float4*)(dv + (a << 3));
            float2 t0 = __half22float2(u2.h[0]);
            float2 t1 = __half22float2(u2.h[1]);
            float2 t2 = __half22float2(u2.h[2]);
            float2 t3 = __half22float2(u2.h[3]);
            zz[a] = t0.x*rr[0] + t0.y*rr[1] + t1.x*rr[2] + t1.y*rr[3]
                  + t2.x*rr[4] + t2.y*rr[5] + t3.x*rr[6] + t3.y*rr[7];
        }
        float4 z0 = make_float4(zz[0], zz[1], zz[2], zz[3]);
        float4 z1 = make_float4(zz[4], zz[5], zz[6], zz[7]);
        z[f4] = z0; z[f4 + 1] = z1;
        writeHalf4(zh, f4, z0);
        writeHalf4(zh, f4 + 1, z1);
        float d = rr[0]*zz[0] + rr[1]*zz[1] + rr[2]*zz[2] + rr[3]*zz[3]
                + rr[4]*zz[4] + rr[5]*zz[5] + rr[6]*zz[6] + rr[7]*zz[7];
        if (bb == 0) s0 = d; else s1 = d;
    }
    blockReduceAdd2(s0, s1, rho0);
}

// C-G PCG update: thread per (m,b), grid-stride. Scalars once/block.
// p = z + beta p; q = w + beta q; x += alpha p; r -= alpha q;
// z = Dinv r (+zh); rho_next = r.z. Last iter: only out = x.
__global__ __launch_bounds__(256) void k_axpy(float4* __restrict__ x,
                                              float4* __restrict__ r,
                                              float4* __restrict__ z,
                                              __half* __restrict__ zh,
                                              float4* __restrict__ p,
                                              float4* __restrict__ q,
                                              const float4* __restrict__ w,
                                              const __half* __restrict__ dinv,
                                              const float* __restrict__ rho_s,
                                              const float* __restrict__ mu_s,
                                              float* __restrict__ fin,
                                              float* __restrict__ rho_next,
                                              int j, int last,
                                              float4* __restrict__ out) {
    __shared__ float sc[4];
    if (threadIdx.x == 0) {
        float2 rho = sumSlots(rho_s);
        float2 mu  = sumSlots(mu_s);
        float b0, b1, al0, al1;
        if (j == 0) {
            b0 = b1 = 0.0f;
            al0 = rho.x / (mu.x + EPSF);
            al1 = rho.y / (mu.y + EPSF);
        } else {
            float ap0 = fin[4*(j-1)+0], ap1 = fin[4*(j-1)+1];
            float rp0 = fin[4*(j-1)+2], rp1 = fin[4*(j-1)+3];
            b0 = rho.x / (rp0 + EPSF);
            b1 = rho.y / (rp1 + EPSF);
            al0 = rho.x / (mu.x - b0 * rho.x / (ap0 + EPSF) + EPSF);
            al1 = rho.y / (mu.y - b1 * rho.y / (ap1 + EPSF) + EPSF);
        }
        if (!last && blockIdx.x == 0) {
            fin[4*j] = al0; fin[4*j+1] = al1; fin[4*j+2] = rho.x; fin[4*j+3] = rho.y;
        }
        sc[0] = al0; sc[1] = al1; sc[2] = b0; sc[3] = b1;
    }
    __syncthreads();
    float al0 = sc[0], al1 = sc[1], b0s = sc[2], b1s = sc[3];
    float s0 = 0.f, s1 = 0.f;
    for (int u = blockIdx.x * blockDim.x + threadIdx.x; u < M_NODES * 2;
         u += gridDim.x * blockDim.x) {
        int m = u >> 1, bb = u & 1;
        int f4 = (m << 2) + (bb << 1);
        float be = bb ? b1s : b0s;
        float al = bb ? al1 : al0;
        float4 zv0 = z[f4], zv1 = z[f4 + 1];
        float4 wv0 = w[f4], wv1 = w[f4 + 1];
        float4 pn0, pn1, qn0, qn1;
        if (j == 0) { pn0 = zv0; pn1 = zv1; qn0 = wv0; qn1 = wv1; }
        else {
            float4 pv0 = p[f4], pv1 = p[f4 + 1];
            float4 qv0 = q[f4], qv1 = q[f4 + 1];
            pn0 = make_float4(zv0.x + be*pv0.x, zv0.y + be*pv0.y, zv0.z + be*pv0.z, zv0.w + be*pv0.w);
            pn1 = make_float4(zv1.x + be*pv1.x, zv1.y + be*pv1.y, zv1.z + be*pv1.z, zv1.w + be*pv1.w);
            qn0 = make_float4(wv0.x + be*qv0.x, wv0.y + be*qv0.y, wv0.z + be*qv0.z, wv0.w + be*qv0.w);
            qn1 = make_float4(wv1.x + be*qv1.x, wv1.y + be*qv1.y, wv1.z + be*qv1.z, wv1.w + be*qv1.w);
        }
        float4 xv0 = x[f4], xv1 = x[f4 + 1];
        float4 xn0 = make_float4(xv0.x + al*pn0.x, xv0.y + al*pn0.y, xv0.z + al*pn0.z, xv0.w + al*pn0.w);
        float4 xn1 = make_float4(xv1.x + al*pn1.x, xv1.y + al*pn1.y, xv1.z + al*pn1.z, xv1.w + al*pn1.w);
        if (last) {
            out[bb * (PER_B / 4) + (m << 1)] = xn0;
            out[bb * (PER_B / 4) + (m << 1) + 1] = xn1;
        } else {
            float4 rv0 = r[f4], rv1 = r[f4 + 1];
            float rr[8];
            rr[0] = rv0.x - al*qn0.x; rr[1] = rv0.y - al*qn0.y;
            rr[2] = rv0.z - al*qn0.z; rr[3] = rv0.w - al*qn0.w;
            rr[4] = rv1.x - al*qn1.x; rr[5] = rv1.y - al*qn1.y;
            rr[6] = rv1.z - al*qn1.z; rr[7] = rv1.w - al*qn1.w;
            x[f4] = xn0; x[f4 + 1] = xn1;
            r[f4] = make_float4(rr[0], rr[1], rr[2], rr[3]);
            r[f4 + 1] = make_float4(rr[4], rr[5], rr[6], rr[7]);
            p[f4] = pn0; p[f4 + 1] = pn1;
            q[f4] = qn0; q[f4 + 1] = qn1;
            float zz[8];
            const __half* dv = dinv + ((size_t)m << 6);
#pragma unroll
            for (int a = 0; a < 8; ++a) {
                union { float4 f; __half2 h[4]; } u2;
                u2.f = *(const float4*)(dv + (a << 3));
                float2 t0 = __half22float2(u2.h[0]);
                float2 t1 = __half22float2(u2.h[1]);
                float2 t2 = __half22float2(u2.h[2]);
                float2 t3 = __half22float2(u2.h[3]);
                zz[a] = t0.x*rr[0] + t0.y*rr[1] + t1.x*rr[2] + t1.y*rr[3]
                      + t2.x*rr[4] + t2.y*rr[5] + t3.x*rr[6] + t3.y*rr[7];
            }
            float4 z0 = make_float4(zz[0], zz[1], zz[2], zz[3]);
            float4 z1 = make_float4(zz[4], zz[5], zz[6], zz[7]);
            z[f4] = z0; z[f4 + 1] = z1;
            writeHalf4(zh, f4, z0);
            writeHalf4(zh, f4 + 1, z1);
            float d = rr[0]*zz[0] + rr[1]*zz[1] + rr[2]*zz[2] + rr[3]*zz[3]
                    + rr[4]*zz[4] + rr[5]*zz[5] + rr[6]*zz[6] + rr[7]*zz[7];
            if (bb == 0) s0 += d; else s1 += d;
        }
    }
    if (!last) blockReduceAdd2(s0, s1, rho_next);
}

extern "C" void kernel_launch(void* const* d_in, const int* in_sizes, int n_in,
                              void* d_out, int out_size, void* d_ws, size_t ws_size,
                              hipStream_t stream) {
    const float* c0 = (const float*)d_in[0];
    const int* src  = (const int*)d_in[1];
    const int* dst  = (const int*)d_in[2];
    const float* Rs = (const float*)d_in[3];
    const float* Rd = (const float*)d_in[4];

    char* wsp = (char*)d_ws;
    size_t o = 0;
    auto alloc = [&](size_t bytes) { char* c = wsp + o; o = (o + bytes + 255) & ~(size_t)255; return c; };
    float* r      = (float*)alloc(VEC_N * 4);
    float* wv     = (float*)alloc(VEC_N * 4);
    float* p      = (float*)alloc(VEC_N * 4);
    float* q      = (float*)alloc(VEC_N * 4);
    float* x      = (float*)alloc(VEC_N * 4);
    float* z      = (float*)alloc(VEC_N * 4);
    __half* zh    = (__half*)alloc(VEC_N * 2);
    __half* bh    = (__half*)alloc(VEC_N * 2);
    float* scal   = (float*)alloc(4096 * 4);
    int*   cnt    = (int*)alloc(M_NODES * 4);
    int*   offa   = (int*)alloc((M_NODES + 1) * 4);
    int*   cursor = (int*)alloc(M_NODES * 4);
    int*   partial= (int*)alloc(M_NODES * 4);
    int*   btot   = (int*)alloc(SCB * 4);
    int*   boff   = (int*)alloc(SCB * 4);
    int*   pos0   = (int*)alloc(E_EDGES * 4);
    int*   pos1   = (int*)alloc(E_EDGES * 4);
    int*   wk     = (int*)alloc(N_INC * 4);
    int*   nb     = (int*)alloc(N_INC * 4);
    __half* diag  = (__half*)alloc((size_t)M_NODES * 64 * 2);
    __half* dinv  = (__half*)alloc((size_t)M_NODES * 64 * 2);
    __half* Wc    = (__half*)alloc((size_t)N_INC * 64 * 2);
    size_t ghBytes = (size_t)N_INC * 64 * 2;
    int haveGH = (o + ghBytes) <= ws_size;
    __half* GHc = haveGH ? (__half*)alloc(ghBytes) : (__half*)Wc;

    const int BLK = 256;
    const int grid_v  = (N4 + BLK - 1) / BLK;
    const int grid_e  = (E_EDGES + BLK - 1) / BLK;
    const int grid_e8 = (E_EDGES * 8 + BLK - 1) / BLK;
    const int grid_m8 = (M_NODES * 8 + BLK - 1) / BLK;
    const int grid_mw = (M_NODES * 64 + BLK - 1) / BLK;
    const int grid_u  = (M_NODES * 2 + BLK - 1) / BLK;
    const int MVB     = 2048;
    const int AXB     = 392;

    float* RHO = scal;             // RHO(t) = scal + 64*t
    float* MU  = scal + 1024;      // MU(t)  = scal + 1024 + 64*t
    float* FIN = scal + 3968;

    // ---- precompute (rebuilt every call) ----
    k_prolog<<<grid_v, BLK, 0, stream>>>(scal, cnt, (const float4*)c0, bh);
    k_hist<<<grid_e, BLK, 0, stream>>>(src, dst, cnt);
    k_scanA<<<SCB, SCT, 0, stream>>>(cnt, partial, btot);
    k_scanB<<<1, SCT, 0, stream>>>(btot, boff, offa);
    k_scanC<<<SCB, SCT, 0, stream>>>(partial, boff, offa, cursor);
    k_scatter<<<grid_e, BLK, 0, stream>>>(src, dst, cursor, pos0, pos1, nb, wk);
    k_buildC<<<grid_e8, BLK, 0, stream>>>(Rs, Rd, pos0, pos1, Wc, GHc, haveGH);
    if (haveGH)
        k_diagS<<<grid_mw, BLK, 0, stream>>>(offa, GHc, diag);
    else
        k_diagR<<<grid_m8, BLK, 0, stream>>>(offa, wk, Rs, Rd, diag);
    k_dinv<<<(M_NODES + 63) / 64, 64, 0, stream>>>(diag, dinv);

    // ---- init: w = A b; r,x,z,zh,rho0 ----
    k_mv<<<MVB, BLK, 0, stream>>>(bh, wv, offa, nb, Wc, diag, MU + 64 * 12);
    k_init0<<<grid_u, BLK, 0, stream>>>((const float4*)c0, (const float4*)wv,
                                        (float4*)r, (float4*)x, (float4*)z, zh,
                                        dinv, RHO);

    // ---- C-G PCG: 2 kernels/iter, matvec on zh ----
    for (int t = 0; t < CG_ITERS; ++t) {
        k_mv<<<MVB, BLK, 0, stream>>>(zh, wv, offa, nb, Wc, diag, MU + 64 * t);
        k_axpy<<<AXB, BLK, 0, stream>>>((float4*)x, (float4*)r, (float4*)z, zh,
                                        (float4*)p, (float4*)q, (const float4*)wv,
                                        dinv, RHO + 64 * t, MU + 64 * t, FIN,
                                        RHO + 64 * (t + 1), t,
                                        (t == CG_ITERS - 1) ? 1 : 0,
                                        (float4*)d_out);
    }
}